// Round 1
// baseline (2691.218 us; speedup 1.0000x reference)
//
#include <hip/hip_runtime.h>

#define N_TOK 21952          // 28*28*28
#define NR    343            // 7*7*7
#define ATT_SCALE 0.17677669529663687f   // 32^-0.5

// ---------------------------------------------------------------------------
// Generic tiled fp32 GEMM: out[M,Nc] = (A [+ A2]) @ W^T [+ bias]
// W is [Nc, K] row-major. 64x64 tile, BK=16, 256 threads, 4x4 per thread.
// atomic=1: atomicAdd into out (split-K via gridDim.z, kLen = K/gridDim.z).
// ---------------------------------------------------------------------------
__global__ __launch_bounds__(256) void gemm_kernel(
    const float* __restrict__ A, const float* __restrict__ A2,
    const float* __restrict__ W, const float* __restrict__ bias,
    float* __restrict__ out, int M, int Nc, int K, int kLen, int atomic)
{
    __shared__ float As[16][64];
    __shared__ float Bs[16][64];
    const int tid = threadIdx.x;
    const int gm0 = blockIdx.x * 64;
    const int gn0 = blockIdx.y * 64;
    const int kbeg = blockIdx.z * kLen;
    const int tx = tid & 15, ty = tid >> 4;
    const int lm = tid >> 2;          // 0..63
    const int lk = (tid & 3) << 2;    // 0,4,8,12

    float acc[4][4];
#pragma unroll
    for (int i = 0; i < 4; i++)
#pragma unroll
        for (int j = 0; j < 4; j++) acc[i][j] = 0.f;

    for (int kk = kbeg; kk < kbeg + kLen; kk += 16) {
        int am = gm0 + lm;
        float4 av = make_float4(0.f, 0.f, 0.f, 0.f);
        if (am < M) {
            av = *(const float4*)(A + (size_t)am * K + kk + lk);
            if (A2) {
                float4 b4 = *(const float4*)(A2 + (size_t)am * K + kk + lk);
                av.x += b4.x; av.y += b4.y; av.z += b4.z; av.w += b4.w;
            }
        }
        As[lk + 0][lm] = av.x; As[lk + 1][lm] = av.y;
        As[lk + 2][lm] = av.z; As[lk + 3][lm] = av.w;

        int wn = gn0 + lm;   // Nc is always a multiple of 64 here
        float4 wv = *(const float4*)(W + (size_t)wn * K + kk + lk);
        Bs[lk + 0][lm] = wv.x; Bs[lk + 1][lm] = wv.y;
        Bs[lk + 2][lm] = wv.z; Bs[lk + 3][lm] = wv.w;
        __syncthreads();

#pragma unroll
        for (int k = 0; k < 16; k++) {
            float a[4], b[4];
#pragma unroll
            for (int i = 0; i < 4; i++) a[i] = As[k][ty * 4 + i];
#pragma unroll
            for (int j = 0; j < 4; j++) b[j] = Bs[k][tx * 4 + j];
#pragma unroll
            for (int i = 0; i < 4; i++)
#pragma unroll
                for (int j = 0; j < 4; j++) acc[i][j] += a[i] * b[j];
        }
        __syncthreads();
    }

#pragma unroll
    for (int i = 0; i < 4; i++) {
        int m = gm0 + ty * 4 + i;
        if (m >= M) continue;
#pragma unroll
        for (int j = 0; j < 4; j++) {
            int n = gn0 + tx * 4 + j;
            float v = acc[i][j];
            if (atomic) {
                atomicAdd(out + (size_t)m * Nc + n, v);
            } else {
                if (bias) v += bias[n];
                out[(size_t)m * Nc + n] = v;
            }
        }
    }
}

// ---------------------------------------------------------------------------
// im2col for stride-4 4x4x4 VALID conv (stride==kernel => pure permutation).
// out[p][ci*64 + tap] = x[n(p,tap)][ci],  tap = kz*16+ky*4+kx
// ---------------------------------------------------------------------------
__global__ __launch_bounds__(256) void im2col_kernel(
    const float* __restrict__ x, float* __restrict__ out)
{
    int idx = blockIdx.x * 256 + threadIdx.x;    // < 343*16384 (exact grid)
    int p   = idx >> 14;
    int k   = idx & 16383;
    int ci  = k >> 6;
    int tap = k & 63;
    int kz = tap >> 4, ky = (tap >> 2) & 3, kx = tap & 3;
    int pz = p / 49, pr = p % 49, py = pr / 7, px = pr % 7;
    int n = (pz * 4 + kz) * 784 + (py * 4 + ky) * 28 + (px * 4 + kx);
    out[idx] = x[(size_t)n * 256 + ci];
}

__global__ __launch_bounds__(256) void init_bias_kernel(
    const float* __restrict__ b, float* __restrict__ out)
{
    out[blockIdx.x * 256 + threadIdx.x] = b[threadIdx.x];
}

// ---------------------------------------------------------------------------
// Depthwise 3x3x3 SAME conv over [28,28,28] in [N,C] layout. 8 voxels/block.
// ---------------------------------------------------------------------------
__global__ __launch_bounds__(256) void dwconv_kernel(
    const float* __restrict__ y, const float* __restrict__ w,
    const float* __restrict__ bias, float* __restrict__ out)
{
    __shared__ float sw[256 * 27];
    int tid = threadIdx.x;
    for (int i = tid; i < 256 * 27; i += 256) sw[i] = w[i];
    __syncthreads();
    int c = tid;
    float bc = bias[c];
    for (int q = 0; q < 8; q++) {
        int n = blockIdx.x * 8 + q;
        int z = n / 784, r = n % 784, yy = r / 28, xx = r % 28;
        float acc = bc;
#pragma unroll
        for (int kz = 0; kz < 3; kz++) {
            int zz = z + kz - 1; if ((unsigned)zz >= 28u) continue;
#pragma unroll
            for (int ky = 0; ky < 3; ky++) {
                int y2 = yy + ky - 1; if ((unsigned)y2 >= 28u) continue;
#pragma unroll
                for (int kx = 0; kx < 3; kx++) {
                    int x2 = xx + kx - 1; if ((unsigned)x2 >= 28u) continue;
                    acc += y[(size_t)(zz * 784 + y2 * 28 + x2) * 256 + c]
                         * sw[c * 27 + kz * 9 + ky * 3 + kx];
                }
            }
        }
        out[(size_t)n * 256 + c] = acc;
    }
}

// ---------------------------------------------------------------------------
// LayerNorm (over C=256) + exact GELU.  One block per row.
// ---------------------------------------------------------------------------
__global__ __launch_bounds__(256) void ln_gelu_kernel(
    const float* __restrict__ in, const float* __restrict__ g,
    const float* __restrict__ b, float* __restrict__ out)
{
    int row = blockIdx.x, c = threadIdx.x;
    float v = in[row * 256 + c];
    float s = v, s2 = v * v;
#pragma unroll
    for (int off = 1; off < 64; off <<= 1) {
        s  += __shfl_xor(s,  off);
        s2 += __shfl_xor(s2, off);
    }
    __shared__ float ws[4], ws2[4];
    int wave = c >> 6, lane = c & 63;
    if (lane == 0) { ws[wave] = s; ws2[wave] = s2; }
    __syncthreads();
    float mean = (ws[0] + ws[1] + ws[2] + ws[3]) * (1.f / 256.f);
    float m2   = (ws2[0] + ws2[1] + ws2[2] + ws2[3]) * (1.f / 256.f);
    float var  = m2 - mean * mean;
    float xn = (v - mean) * rsqrtf(var + 1e-5f) * g[c] + b[c];
    out[row * 256 + c] = 0.5f * xn * (1.f + erff(xn * 0.70710678118654752f));
}

// ---------------------------------------------------------------------------
// Branch 1: global attention vs 343 spatially-reduced keys.
// One wave per (query n, head h).  Online softmax, flash-style.
// q1: [N,128] (col = h*32+d); kv1: [343,256] (k cols 0..127, v cols 128..255)
// writes o[n, h*32+d]  (cols 0..127)
// ---------------------------------------------------------------------------
__global__ __launch_bounds__(256) void attn1_kernel(
    const float* __restrict__ q1, const float* __restrict__ kv1,
    float* __restrict__ o)
{
    int n = blockIdx.x;
    int h = threadIdx.x >> 6;
    int lane = threadIdx.x & 63;
    const float NEG_INF = -__builtin_inff();

    const float* qp = q1 + (size_t)n * 128 + h * 32;
    float4 q[8];
#pragma unroll
    for (int i = 0; i < 8; i++) q[i] = *(const float4*)(qp + i * 4);

    float mrun = NEG_INF, lrun = 0.f;
    float acc[32];
#pragma unroll
    for (int d = 0; d < 32; d++) acc[d] = 0.f;

    for (int c0 = 0; c0 < NR; c0 += 64) {
        int m = c0 + lane;
        bool valid = (m < NR);
        float s = NEG_INF;
        float4 vv[8];
#pragma unroll
        for (int i = 0; i < 8; i++) vv[i] = make_float4(0.f, 0.f, 0.f, 0.f);
        if (valid) {
            const float* kp = kv1 + (size_t)m * 256 + h * 32;
            float dot = 0.f;
#pragma unroll
            for (int i = 0; i < 8; i++) {
                float4 k4 = *(const float4*)(kp + i * 4);
                dot += q[i].x * k4.x + q[i].y * k4.y + q[i].z * k4.z + q[i].w * k4.w;
            }
            s = dot * ATT_SCALE;
            const float* vp = kv1 + (size_t)m * 256 + 128 + h * 32;
#pragma unroll
            for (int i = 0; i < 8; i++) vv[i] = *(const float4*)(vp + i * 4);
        }
        float cm = s;
#pragma unroll
        for (int off = 1; off < 64; off <<= 1) cm = fmaxf(cm, __shfl_xor(cm, off));
        float nm = fmaxf(mrun, cm);
        float alpha = expf(mrun - nm);          // chunk0: exp(-inf)=0
        float p = valid ? expf(s - nm) : 0.f;
        float ps = p;
#pragma unroll
        for (int off = 1; off < 64; off <<= 1) ps += __shfl_xor(ps, off);
        lrun = lrun * alpha + ps;
        mrun = nm;
#pragma unroll
        for (int i = 0; i < 8; i++) {
            acc[i * 4 + 0] = acc[i * 4 + 0] * alpha + p * vv[i].x;
            acc[i * 4 + 1] = acc[i * 4 + 1] * alpha + p * vv[i].y;
            acc[i * 4 + 2] = acc[i * 4 + 2] * alpha + p * vv[i].z;
            acc[i * 4 + 3] = acc[i * 4 + 3] * alpha + p * vv[i].w;
        }
    }
#pragma unroll
    for (int d = 0; d < 32; d++) {
        float t = acc[d];
#pragma unroll
        for (int off = 1; off < 64; off <<= 1) t += __shfl_xor(t, off);
        acc[d] = t;
    }
    if (lane == 0) {
        float inv = 1.f / lrun;
        float* op = o + (size_t)n * 256 + h * 32;
#pragma unroll
        for (int i = 0; i < 8; i++) {
            float4 r = make_float4(acc[i * 4 + 0] * inv, acc[i * 4 + 1] * inv,
                                   acc[i * 4 + 2] * inv, acc[i * 4 + 3] * inv);
            *(float4*)(op + i * 4) = r;
        }
    }
}

// ---------------------------------------------------------------------------
// Branch 2: windowed attention. wi = h*64 + zb*16 + yb*4 + xb (256 windows),
// token t = wz*49+wy*7+wx within 7^3 window. One wave per (window, query t).
// q2: [N,128]; kv2: [N,256] (k cols 0..127, v cols 128..255).
// writes o[nq, 128 + h*32 + d]  (cols 128..255)
// ---------------------------------------------------------------------------
__global__ __launch_bounds__(256) void attn2_kernel(
    const float* __restrict__ q2, const float* __restrict__ kv2,
    float* __restrict__ o)
{
    int wi = blockIdx.x;
    int h  = wi >> 6;
    int zb = (wi >> 4) & 3, yb = (wi >> 2) & 3, xb = wi & 3;
    int t  = blockIdx.y * 4 + (threadIdx.x >> 6);
    int lane = threadIdx.x & 63;
    if (t >= NR) return;
    const float NEG_INF = -__builtin_inff();

    int wz = t / 49, tr = t % 49, wy = tr / 7, wx = tr % 7;
    int nq = (zb * 7 + wz) * 784 + (yb * 7 + wy) * 28 + (xb * 7 + wx);

    const float* qp = q2 + (size_t)nq * 128 + h * 32;
    float4 q[8];
#pragma unroll
    for (int i = 0; i < 8; i++) q[i] = *(const float4*)(qp + i * 4);

    float mrun = NEG_INF, lrun = 0.f;
    float acc[32];
#pragma unroll
    for (int d = 0; d < 32; d++) acc[d] = 0.f;

    for (int c0 = 0; c0 < NR; c0 += 64) {
        int m = c0 + lane;
        bool valid = (m < NR);
        float s = NEG_INF;
        float4 vv[8];
#pragma unroll
        for (int i = 0; i < 8; i++) vv[i] = make_float4(0.f, 0.f, 0.f, 0.f);
        if (valid) {
            int mz = m / 49, mr = m % 49, my = mr / 7, mx = mr % 7;
            int nk = (zb * 7 + mz) * 784 + (yb * 7 + my) * 28 + (xb * 7 + mx);
            const float* kp = kv2 + (size_t)nk * 256 + h * 32;
            float dot = 0.f;
#pragma unroll
            for (int i = 0; i < 8; i++) {
                float4 k4 = *(const float4*)(kp + i * 4);
                dot += q[i].x * k4.x + q[i].y * k4.y + q[i].z * k4.z + q[i].w * k4.w;
            }
            s = dot * ATT_SCALE;
            const float* vp = kv2 + (size_t)nk * 256 + 128 + h * 32;
#pragma unroll
            for (int i = 0; i < 8; i++) vv[i] = *(const float4*)(vp + i * 4);
        }
        float cm = s;
#pragma unroll
        for (int off = 1; off < 64; off <<= 1) cm = fmaxf(cm, __shfl_xor(cm, off));
        float nm = fmaxf(mrun, cm);
        float alpha = expf(mrun - nm);
        float p = valid ? expf(s - nm) : 0.f;
        float ps = p;
#pragma unroll
        for (int off = 1; off < 64; off <<= 1) ps += __shfl_xor(ps, off);
        lrun = lrun * alpha + ps;
        mrun = nm;
#pragma unroll
        for (int i = 0; i < 8; i++) {
            acc[i * 4 + 0] = acc[i * 4 + 0] * alpha + p * vv[i].x;
            acc[i * 4 + 1] = acc[i * 4 + 1] * alpha + p * vv[i].y;
            acc[i * 4 + 2] = acc[i * 4 + 2] * alpha + p * vv[i].z;
            acc[i * 4 + 3] = acc[i * 4 + 3] * alpha + p * vv[i].w;
        }
    }
#pragma unroll
    for (int d = 0; d < 32; d++) {
        float tt = acc[d];
#pragma unroll
        for (int off = 1; off < 64; off <<= 1) tt += __shfl_xor(tt, off);
        acc[d] = tt;
    }
    if (lane == 0) {
        float inv = 1.f / lrun;
        float* op = o + (size_t)nq * 256 + 128 + h * 32;
#pragma unroll
        for (int i = 0; i < 8; i++) {
            float4 r = make_float4(acc[i * 4 + 0] * inv, acc[i * 4 + 1] * inv,
                                   acc[i * 4 + 2] * inv, acc[i * 4 + 3] * inv);
            *(float4*)(op + i * 4) = r;
        }
    }
}

// ---------------------------------------------------------------------------
extern "C" void kernel_launch(void* const* d_in, const int* in_sizes, int n_in,
                              void* d_out, int out_size, void* d_ws, size_t ws_size,
                              hipStream_t stream)
{
    const float* x       = (const float*)d_in[0];
    // d_in[1..3] = H, W, D (hard-coded 28)
    const float* lepe_w  = (const float*)d_in[4];
    const float* lepe_b  = (const float*)d_in[5];
    const float* lconv_w = (const float*)d_in[6];
    const float* lconv_b = (const float*)d_in[7];
    const float* sr_w    = (const float*)d_in[8];
    const float* sr_b    = (const float*)d_in[9];
    const float* norm_g  = (const float*)d_in[10];
    const float* norm_b  = (const float*)d_in[11];
    const float* q1_w    = (const float*)d_in[12];
    const float* kv1_w   = (const float*)d_in[13];
    const float* q2_w    = (const float*)d_in[14];
    const float* kv2_w   = (const float*)d_in[15];
    const float* proj_w  = (const float*)d_in[16];
    const float* proj_b  = (const float*)d_in[17];
    float* out = (float*)d_out;

    const size_t NC = (size_t)N_TOK * 256;
    float* ws   = (float*)d_ws;
    float* buf0 = ws;                          // y, later kv2
    float* buf1 = buf0 + NC;                   // lepe
    float* buf2 = buf1 + NC;                   // im2col, later o (concat)
    float* buf3 = buf2 + NC;                   // q1, later q2
    float* buf4 = buf3 + (size_t)N_TOK * 128;  // sr conv out [343,256]
    float* buf5 = buf4 + NR * 256;             // x1 [343,256]
    float* buf6 = buf5 + NR * 256;             // kv1 [343,256]
    size_t need = (3 * NC + (size_t)N_TOK * 128 + 3 * (size_t)NR * 256) * sizeof(float);
    if (ws_size < need) return;  // would fail validation loudly rather than corrupt

    // y = x @ lepe_w^T + lepe_b
    gemm_kernel<<<dim3(343, 4, 1), 256, 0, stream>>>(x, nullptr, lepe_w, lepe_b,
                                                     buf0, N_TOK, 256, 256, 256, 0);
    // lepe = depthwise conv(y)
    dwconv_kernel<<<dim3(2744), 256, 0, stream>>>(buf0, lconv_w, lconv_b, buf1);
    // im2col of x for SR conv
    im2col_kernel<<<dim3(21952), 256, 0, stream>>>(x, buf2);
    // srout = bias, then split-K GEMM accumulate
    init_bias_kernel<<<dim3(NR), 256, 0, stream>>>(sr_b, buf4);
    gemm_kernel<<<dim3(6, 4, 16), 256, 0, stream>>>(buf2, nullptr, sr_w, nullptr,
                                                    buf4, NR, 256, 16384, 1024, 1);
    // x1 = gelu(layernorm(srout))
    ln_gelu_kernel<<<dim3(NR), 256, 0, stream>>>(buf4, norm_g, norm_b, buf5);
    // kv1 = x1 @ kv1_w^T
    gemm_kernel<<<dim3(6, 4, 1), 256, 0, stream>>>(buf5, nullptr, kv1_w, nullptr,
                                                   buf6, NR, 256, 256, 256, 0);
    // q1 = x @ q1_w^T
    gemm_kernel<<<dim3(343, 2, 1), 256, 0, stream>>>(x, nullptr, q1_w, nullptr,
                                                     buf3, N_TOK, 128, 256, 256, 0);
    // branch-1 attention -> o[:, :128]   (buf2 free after SR gemm)
    attn1_kernel<<<dim3(N_TOK), 256, 0, stream>>>(buf3, buf6, buf2);
    // q2 = x @ q2_w^T (reuse q buffer)
    gemm_kernel<<<dim3(343, 2, 1), 256, 0, stream>>>(x, nullptr, q2_w, nullptr,
                                                     buf3, N_TOK, 128, 256, 256, 0);
    // kv2 = x @ kv2_w^T (reuse y buffer)
    gemm_kernel<<<dim3(343, 4, 1), 256, 0, stream>>>(x, nullptr, kv2_w, nullptr,
                                                     buf0, N_TOK, 256, 256, 256, 0);
    // branch-2 windowed attention -> o[:, 128:]
    attn2_kernel<<<dim3(256, 86), 256, 0, stream>>>(buf3, buf0, buf2);
    // out = (o + lepe) @ proj_w^T + proj_b
    gemm_kernel<<<dim3(343, 4, 1), 256, 0, stream>>>(buf2, buf1, proj_w, proj_b,
                                                     out, N_TOK, 256, 256, 256, 0);
}

// Round 2
// 908.401 us; speedup vs baseline: 2.9626x; 2.9626x over previous
//
#include <hip/hip_runtime.h>

#define N_TOK 21952          // 28*28*28
#define NR    343            // 7*7*7
#define ATT_SCALE 0.17677669529663687f   // 32^-0.5
#define KC    176            // key chunk staged in LDS (45 KB)

// ---------------------------------------------------------------------------
// Generic tiled fp32 GEMM: out[M,Nc] = (A [+ A2]) @ W^T [+ bias]
// W is [Nc, K] row-major. 64x64 tile, BK=16, 256 threads, 4x4 per thread.
// atomic=1: atomicAdd into out (split-K via gridDim.z, kLen = K/gridDim.z).
// ---------------------------------------------------------------------------
__global__ __launch_bounds__(256) void gemm_kernel(
    const float* __restrict__ A, const float* __restrict__ A2,
    const float* __restrict__ W, const float* __restrict__ bias,
    float* __restrict__ out, int M, int Nc, int K, int kLen, int atomic)
{
    __shared__ float As[16][64];
    __shared__ float Bs[16][64];
    const int tid = threadIdx.x;
    const int gm0 = blockIdx.x * 64;
    const int gn0 = blockIdx.y * 64;
    const int kbeg = blockIdx.z * kLen;
    const int tx = tid & 15, ty = tid >> 4;
    const int lm = tid >> 2;          // 0..63
    const int lk = (tid & 3) << 2;    // 0,4,8,12

    float acc[4][4];
#pragma unroll
    for (int i = 0; i < 4; i++)
#pragma unroll
        for (int j = 0; j < 4; j++) acc[i][j] = 0.f;

    for (int kk = kbeg; kk < kbeg + kLen; kk += 16) {
        int am = gm0 + lm;
        float4 av = make_float4(0.f, 0.f, 0.f, 0.f);
        if (am < M) {
            av = *(const float4*)(A + (size_t)am * K + kk + lk);
            if (A2) {
                float4 b4 = *(const float4*)(A2 + (size_t)am * K + kk + lk);
                av.x += b4.x; av.y += b4.y; av.z += b4.z; av.w += b4.w;
            }
        }
        As[lk + 0][lm] = av.x; As[lk + 1][lm] = av.y;
        As[lk + 2][lm] = av.z; As[lk + 3][lm] = av.w;

        int wn = gn0 + lm;   // Nc is always a multiple of 64 here
        float4 wv = *(const float4*)(W + (size_t)wn * K + kk + lk);
        Bs[lk + 0][lm] = wv.x; Bs[lk + 1][lm] = wv.y;
        Bs[lk + 2][lm] = wv.z; Bs[lk + 3][lm] = wv.w;
        __syncthreads();

#pragma unroll
        for (int k = 0; k < 16; k++) {
            float a[4], b[4];
#pragma unroll
            for (int i = 0; i < 4; i++) a[i] = As[k][ty * 4 + i];
#pragma unroll
            for (int j = 0; j < 4; j++) b[j] = Bs[k][tx * 4 + j];
#pragma unroll
            for (int i = 0; i < 4; i++)
#pragma unroll
                for (int j = 0; j < 4; j++) acc[i][j] += a[i] * b[j];
        }
        __syncthreads();
    }

#pragma unroll
    for (int i = 0; i < 4; i++) {
        int m = gm0 + ty * 4 + i;
        if (m >= M) continue;
#pragma unroll
        for (int j = 0; j < 4; j++) {
            int n = gn0 + tx * 4 + j;
            float v = acc[i][j];
            if (atomic) {
                atomicAdd(out + (size_t)m * Nc + n, v);
            } else {
                if (bias) v += bias[n];
                out[(size_t)m * Nc + n] = v;
            }
        }
    }
}

// ---------------------------------------------------------------------------
// im2col for stride-4 4x4x4 VALID conv (stride==kernel => pure permutation).
// ---------------------------------------------------------------------------
__global__ __launch_bounds__(256) void im2col_kernel(
    const float* __restrict__ x, float* __restrict__ out)
{
    int idx = blockIdx.x * 256 + threadIdx.x;    // < 343*16384 (exact grid)
    int p   = idx >> 14;
    int k   = idx & 16383;
    int ci  = k >> 6;
    int tap = k & 63;
    int kz = tap >> 4, ky = (tap >> 2) & 3, kx = tap & 3;
    int pz = p / 49, pr = p % 49, py = pr / 7, px = pr % 7;
    int n = (pz * 4 + kz) * 784 + (py * 4 + ky) * 28 + (px * 4 + kx);
    out[idx] = x[(size_t)n * 256 + ci];
}

__global__ __launch_bounds__(256) void init_bias_kernel(
    const float* __restrict__ b, float* __restrict__ out)
{
    out[blockIdx.x * 256 + threadIdx.x] = b[threadIdx.x];
}

// ---------------------------------------------------------------------------
// Depthwise 3x3x3 SAME conv over [28,28,28] in [N,C] layout. 8 voxels/block.
// ---------------------------------------------------------------------------
__global__ __launch_bounds__(256) void dwconv_kernel(
    const float* __restrict__ y, const float* __restrict__ w,
    const float* __restrict__ bias, float* __restrict__ out)
{
    __shared__ float sw[256 * 27];
    int tid = threadIdx.x;
    for (int i = tid; i < 256 * 27; i += 256) sw[i] = w[i];
    __syncthreads();
    int c = tid;
    float bc = bias[c];
    for (int q = 0; q < 8; q++) {
        int n = blockIdx.x * 8 + q;
        int z = n / 784, r = n % 784, yy = r / 28, xx = r % 28;
        float acc = bc;
#pragma unroll
        for (int kz = 0; kz < 3; kz++) {
            int zz = z + kz - 1; if ((unsigned)zz >= 28u) continue;
#pragma unroll
            for (int ky = 0; ky < 3; ky++) {
                int y2 = yy + ky - 1; if ((unsigned)y2 >= 28u) continue;
#pragma unroll
                for (int kx = 0; kx < 3; kx++) {
                    int x2 = xx + kx - 1; if ((unsigned)x2 >= 28u) continue;
                    acc += y[(size_t)(zz * 784 + y2 * 28 + x2) * 256 + c]
                         * sw[c * 27 + kz * 9 + ky * 3 + kx];
                }
            }
        }
        out[(size_t)n * 256 + c] = acc;
    }
}

// ---------------------------------------------------------------------------
// LayerNorm (over C=256) + exact GELU.  One block per row.
// ---------------------------------------------------------------------------
__global__ __launch_bounds__(256) void ln_gelu_kernel(
    const float* __restrict__ in, const float* __restrict__ g,
    const float* __restrict__ b, float* __restrict__ out)
{
    int row = blockIdx.x, c = threadIdx.x;
    float v = in[row * 256 + c];
    float s = v, s2 = v * v;
#pragma unroll
    for (int off = 1; off < 64; off <<= 1) {
        s  += __shfl_xor(s,  off);
        s2 += __shfl_xor(s2, off);
    }
    __shared__ float ws[4], ws2[4];
    int wave = c >> 6, lane = c & 63;
    if (lane == 0) { ws[wave] = s; ws2[wave] = s2; }
    __syncthreads();
    float mean = (ws[0] + ws[1] + ws[2] + ws[3]) * (1.f / 256.f);
    float m2   = (ws2[0] + ws2[1] + ws2[2] + ws2[3]) * (1.f / 256.f);
    float var  = m2 - mean * mean;
    float xn = (v - mean) * rsqrtf(var + 1e-5f) * g[c] + b[c];
    out[row * 256 + c] = 0.5f * xn * (1.f + erff(xn * 0.70710678118654752f));
}

// ---------------------------------------------------------------------------
// Branch 1: global attention vs 343 reduced keys. One THREAD per query.
// grid (86, 4): blockIdx.x = query block (256 queries), blockIdx.y = head.
// K/V staged into LDS in chunks of KC keys; broadcast ds_reads in inner loop;
// per-thread online softmax (no cross-lane ops).
// q1: [N,128]; kv1: [343,256] (K cols 0..127, V cols 128..255).
// writes o[n, h*32+d] (cols 0..127)
// ---------------------------------------------------------------------------
__global__ __launch_bounds__(256) void attn1_kernel(
    const float* __restrict__ q1, const float* __restrict__ kv1,
    float* __restrict__ o)
{
    __shared__ float Ks[KC * 32];
    __shared__ float Vs[KC * 32];
    const int tid = threadIdx.x;
    const int h = blockIdx.y;
    const int n = blockIdx.x * 256 + tid;
    const bool valid = (n < N_TOK);

    float4 q[8];
#pragma unroll
    for (int i = 0; i < 8; i++) q[i] = make_float4(0.f, 0.f, 0.f, 0.f);
    if (valid) {
        const float* qp = q1 + (size_t)n * 128 + h * 32;
#pragma unroll
        for (int i = 0; i < 8; i++) q[i] = *(const float4*)(qp + i * 4);
    }

    float mrun = -__builtin_inff(), lrun = 0.f;
    float acc[32];
#pragma unroll
    for (int d = 0; d < 32; d++) acc[d] = 0.f;

    for (int k0 = 0; k0 < NR; k0 += KC) {
        int cnt = min(KC, NR - k0);
        // cooperative load: cnt rows x (8 K-float4 + 8 V-float4)
        for (int u = tid; u < cnt * 16; u += 256) {
            int r = u >> 4, p = u & 15;
            int col = (p < 8) ? (h * 32 + p * 4) : (128 + h * 32 + (p - 8) * 4);
            float4 v4 = *(const float4*)(kv1 + (size_t)(k0 + r) * 256 + col);
            float* dst = (p < 8) ? &Ks[r * 32 + p * 4] : &Vs[r * 32 + (p - 8) * 4];
            *(float4*)dst = v4;
        }
        __syncthreads();
        for (int m = 0; m < cnt; m++) {
            const float* kp = &Ks[m * 32];
            float d0 = 0.f, d1 = 0.f, d2 = 0.f, d3 = 0.f;
#pragma unroll
            for (int i = 0; i < 8; i++) {
                float4 k4 = *(const float4*)(kp + i * 4);
                d0 = fmaf(q[i].x, k4.x, d0);
                d1 = fmaf(q[i].y, k4.y, d1);
                d2 = fmaf(q[i].z, k4.z, d2);
                d3 = fmaf(q[i].w, k4.w, d3);
            }
            float s = ((d0 + d1) + (d2 + d3)) * ATT_SCALE;
            float p;
            if (s > mrun) {
                float alpha = __expf(mrun - s);   // first key: exp(-inf)=0
                mrun = s;
                lrun *= alpha;
#pragma unroll
                for (int d = 0; d < 32; d++) acc[d] *= alpha;
                p = 1.f;
            } else {
                p = __expf(s - mrun);
            }
            lrun += p;
            const float* vp = &Vs[m * 32];
#pragma unroll
            for (int i = 0; i < 8; i++) {
                float4 v4 = *(const float4*)(vp + i * 4);
                acc[i * 4 + 0] = fmaf(p, v4.x, acc[i * 4 + 0]);
                acc[i * 4 + 1] = fmaf(p, v4.y, acc[i * 4 + 1]);
                acc[i * 4 + 2] = fmaf(p, v4.z, acc[i * 4 + 2]);
                acc[i * 4 + 3] = fmaf(p, v4.w, acc[i * 4 + 3]);
            }
        }
        __syncthreads();
    }

    if (valid) {
        float inv = 1.f / lrun;
        float* op = o + (size_t)n * 256 + h * 32;
#pragma unroll
        for (int i = 0; i < 8; i++) {
            float4 r = make_float4(acc[i * 4 + 0] * inv, acc[i * 4 + 1] * inv,
                                   acc[i * 4 + 2] * inv, acc[i * 4 + 3] * inv);
            *(float4*)(op + i * 4) = r;
        }
    }
}

// ---------------------------------------------------------------------------
// Branch 2: windowed attention. One block per (window, head) = 256 blocks,
// block = 384 threads, one THREAD per query token of the 7^3 window.
// q2: [N,128]; kv2: [N,256] (K cols 0..127, V cols 128..255).
// writes o[nq, 128 + h*32 + d]
// ---------------------------------------------------------------------------
__global__ __launch_bounds__(384) void attn2_kernel(
    const float* __restrict__ q2, const float* __restrict__ kv2,
    float* __restrict__ o)
{
    __shared__ float Ks[KC * 32];
    __shared__ float Vs[KC * 32];
    const int tid = threadIdx.x;
    const int wi = blockIdx.x;
    const int h  = wi >> 6;
    const int zb = (wi >> 4) & 3, yb = (wi >> 2) & 3, xb = wi & 3;
    const int t  = tid;
    const bool valid = (t < NR);

    int nq = 0;
    if (valid) {
        int wz = t / 49, tr = t % 49, wy = tr / 7, wx = tr % 7;
        nq = (zb * 7 + wz) * 784 + (yb * 7 + wy) * 28 + (xb * 7 + wx);
    }

    float4 q[8];
#pragma unroll
    for (int i = 0; i < 8; i++) q[i] = make_float4(0.f, 0.f, 0.f, 0.f);
    if (valid) {
        const float* qp = q2 + (size_t)nq * 128 + h * 32;
#pragma unroll
        for (int i = 0; i < 8; i++) q[i] = *(const float4*)(qp + i * 4);
    }

    float mrun = -__builtin_inff(), lrun = 0.f;
    float acc[32];
#pragma unroll
    for (int d = 0; d < 32; d++) acc[d] = 0.f;

    for (int k0 = 0; k0 < NR; k0 += KC) {
        int cnt = min(KC, NR - k0);
        for (int u = tid; u < cnt * 16; u += 384) {
            int r = u >> 4, p = u & 15;
            int m = k0 + r;
            int mz = m / 49, mr = m % 49, my = mr / 7, mx = mr % 7;
            int nk = (zb * 7 + mz) * 784 + (yb * 7 + my) * 28 + (xb * 7 + mx);
            int col = (p < 8) ? (h * 32 + p * 4) : (128 + h * 32 + (p - 8) * 4);
            float4 v4 = *(const float4*)(kv2 + (size_t)nk * 256 + col);
            float* dst = (p < 8) ? &Ks[r * 32 + p * 4] : &Vs[r * 32 + (p - 8) * 4];
            *(float4*)dst = v4;
        }
        __syncthreads();
        for (int m = 0; m < cnt; m++) {
            const float* kp = &Ks[m * 32];
            float d0 = 0.f, d1 = 0.f, d2 = 0.f, d3 = 0.f;
#pragma unroll
            for (int i = 0; i < 8; i++) {
                float4 k4 = *(const float4*)(kp + i * 4);
                d0 = fmaf(q[i].x, k4.x, d0);
                d1 = fmaf(q[i].y, k4.y, d1);
                d2 = fmaf(q[i].z, k4.z, d2);
                d3 = fmaf(q[i].w, k4.w, d3);
            }
            float s = ((d0 + d1) + (d2 + d3)) * ATT_SCALE;
            float p;
            if (s > mrun) {
                float alpha = __expf(mrun - s);
                mrun = s;
                lrun *= alpha;
#pragma unroll
                for (int d = 0; d < 32; d++) acc[d] *= alpha;
                p = 1.f;
            } else {
                p = __expf(s - mrun);
            }
            lrun += p;
            const float* vp = &Vs[m * 32];
#pragma unroll
            for (int i = 0; i < 8; i++) {
                float4 v4 = *(const float4*)(vp + i * 4);
                acc[i * 4 + 0] = fmaf(p, v4.x, acc[i * 4 + 0]);
                acc[i * 4 + 1] = fmaf(p, v4.y, acc[i * 4 + 1]);
                acc[i * 4 + 2] = fmaf(p, v4.z, acc[i * 4 + 2]);
                acc[i * 4 + 3] = fmaf(p, v4.w, acc[i * 4 + 3]);
            }
        }
        __syncthreads();
    }

    if (valid) {
        float inv = 1.f / lrun;
        float* op = o + (size_t)nq * 256 + 128 + h * 32;
#pragma unroll
        for (int i = 0; i < 8; i++) {
            float4 r = make_float4(acc[i * 4 + 0] * inv, acc[i * 4 + 1] * inv,
                                   acc[i * 4 + 2] * inv, acc[i * 4 + 3] * inv);
            *(float4*)(op + i * 4) = r;
        }
    }
}

// ---------------------------------------------------------------------------
extern "C" void kernel_launch(void* const* d_in, const int* in_sizes, int n_in,
                              void* d_out, int out_size, void* d_ws, size_t ws_size,
                              hipStream_t stream)
{
    const float* x       = (const float*)d_in[0];
    const float* lepe_w  = (const float*)d_in[4];
    const float* lepe_b  = (const float*)d_in[5];
    const float* lconv_w = (const float*)d_in[6];
    const float* lconv_b = (const float*)d_in[7];
    const float* sr_w    = (const float*)d_in[8];
    const float* sr_b    = (const float*)d_in[9];
    const float* norm_g  = (const float*)d_in[10];
    const float* norm_b  = (const float*)d_in[11];
    const float* q1_w    = (const float*)d_in[12];
    const float* kv1_w   = (const float*)d_in[13];
    const float* q2_w    = (const float*)d_in[14];
    const float* kv2_w   = (const float*)d_in[15];
    const float* proj_w  = (const float*)d_in[16];
    const float* proj_b  = (const float*)d_in[17];
    float* out = (float*)d_out;

    const size_t NC = (size_t)N_TOK * 256;
    float* ws   = (float*)d_ws;
    float* buf0 = ws;                          // y, later kv2
    float* buf1 = buf0 + NC;                   // lepe
    float* buf2 = buf1 + NC;                   // im2col, later o (concat)
    float* buf3 = buf2 + NC;                   // q1, later q2
    float* buf4 = buf3 + (size_t)N_TOK * 128;  // sr conv out [343,256]
    float* buf5 = buf4 + NR * 256;             // x1 [343,256]
    float* buf6 = buf5 + NR * 256;             // kv1 [343,256]
    size_t need = (3 * NC + (size_t)N_TOK * 128 + 3 * (size_t)NR * 256) * sizeof(float);
    if (ws_size < need) return;

    // y = x @ lepe_w^T + lepe_b
    gemm_kernel<<<dim3(343, 4, 1), 256, 0, stream>>>(x, nullptr, lepe_w, lepe_b,
                                                     buf0, N_TOK, 256, 256, 256, 0);
    // lepe = depthwise conv(y)
    dwconv_kernel<<<dim3(2744), 256, 0, stream>>>(buf0, lconv_w, lconv_b, buf1);
    // im2col of x for SR conv
    im2col_kernel<<<dim3(21952), 256, 0, stream>>>(x, buf2);
    // srout = bias, then split-K GEMM accumulate
    init_bias_kernel<<<dim3(NR), 256, 0, stream>>>(sr_b, buf4);
    gemm_kernel<<<dim3(6, 4, 16), 256, 0, stream>>>(buf2, nullptr, sr_w, nullptr,
                                                    buf4, NR, 256, 16384, 1024, 1);
    // x1 = gelu(layernorm(srout))
    ln_gelu_kernel<<<dim3(NR), 256, 0, stream>>>(buf4, norm_g, norm_b, buf5);
    // kv1 = x1 @ kv1_w^T
    gemm_kernel<<<dim3(6, 4, 1), 256, 0, stream>>>(buf5, nullptr, kv1_w, nullptr,
                                                   buf6, NR, 256, 256, 256, 0);
    // q1 = x @ q1_w^T
    gemm_kernel<<<dim3(343, 2, 1), 256, 0, stream>>>(x, nullptr, q1_w, nullptr,
                                                     buf3, N_TOK, 128, 256, 256, 0);
    // branch-1 attention -> o[:, :128]   (buf2 free after SR gemm)
    attn1_kernel<<<dim3(86, 4), 256, 0, stream>>>(buf3, buf6, buf2);
    // q2 = x @ q2_w^T (reuse q buffer)
    gemm_kernel<<<dim3(343, 2, 1), 256, 0, stream>>>(x, nullptr, q2_w, nullptr,
                                                     buf3, N_TOK, 128, 256, 256, 0);
    // kv2 = x @ kv2_w^T (reuse y buffer)
    gemm_kernel<<<dim3(343, 4, 1), 256, 0, stream>>>(x, nullptr, kv2_w, nullptr,
                                                     buf0, N_TOK, 256, 256, 256, 0);
    // branch-2 windowed attention -> o[:, 128:]
    attn2_kernel<<<dim3(256), 384, 0, stream>>>(buf3, buf0, buf2);
    // out = (o + lepe) @ proj_w^T + proj_b
    gemm_kernel<<<dim3(343, 4, 1), 256, 0, stream>>>(buf2, buf1, proj_w, proj_b,
                                                     out, N_TOK, 256, 256, 256, 0);
}

// Round 3
// 685.593 us; speedup vs baseline: 3.9254x; 1.3250x over previous
//
#include <hip/hip_runtime.h>

#define N_TOK 21952          // 28*28*28
#define NR    343            // 7*7*7
#define ATT_SCALE 0.17677669529663687f   // 32^-0.5
#define KC    176            // key chunk staged in LDS (45 KB)

typedef unsigned short u16;
typedef short  v8s __attribute__((ext_vector_type(8)));
typedef float  v4f __attribute__((ext_vector_type(4)));

__device__ __forceinline__ float bf2f(unsigned u) {
    return __builtin_bit_cast(float, u << 16);
}
__device__ __forceinline__ u16 f2bf(float f) {
    unsigned u = __builtin_bit_cast(unsigned, f);
    u += 0x7fffu + ((u >> 16) & 1u);
    return (u16)(u >> 16);
}
__device__ __forceinline__ unsigned bfadd2(unsigned a, unsigned b) {
    float lo = bf2f(a & 0xffffu) + bf2f(b & 0xffffu);
    float hi = bf2f(a >> 16)     + bf2f(b >> 16);
    return (unsigned)f2bf(lo) | ((unsigned)f2bf(hi) << 16);
}

// ---------------------------------------------------------------------------
// Fused fp32 -> bf16 conversion of x + 7 weight tensors. One float4 / thread.
// ---------------------------------------------------------------------------
#define CSEG0 1404928   // x        (5619712/4)
#define CSEG1 1421312   // + lepe_w (65536/4)
#define CSEG2 1429504   // + q1_w   (32768/4)
#define CSEG3 1437696   // + q2_w
#define CSEG4 1454080   // + kv1_w  (65536/4)
#define CSEG5 1470464   // + kv2_w
#define CSEG6 1486848   // + proj_w
#define CSEG7 2535424   // + sr_w   (4194304/4)

__global__ __launch_bounds__(256) void convert_all_kernel(
    const float* __restrict__ x,   const float* __restrict__ wl,
    const float* __restrict__ wq1, const float* __restrict__ wq2,
    const float* __restrict__ wk1, const float* __restrict__ wk2,
    const float* __restrict__ wp,  const float* __restrict__ wsr,
    u16* xb, u16* bl, u16* bq1, u16* bq2, u16* bk1, u16* bk2, u16* bp, u16* bsr)
{
    int gid = blockIdx.x * 256 + threadIdx.x;
    const float* s; u16* d; int l;
    if      (gid < CSEG0) { s = x;   d = xb;  l = gid; }
    else if (gid < CSEG1) { s = wl;  d = bl;  l = gid - CSEG0; }
    else if (gid < CSEG2) { s = wq1; d = bq1; l = gid - CSEG1; }
    else if (gid < CSEG3) { s = wq2; d = bq2; l = gid - CSEG2; }
    else if (gid < CSEG4) { s = wk1; d = bk1; l = gid - CSEG3; }
    else if (gid < CSEG5) { s = wk2; d = bk2; l = gid - CSEG4; }
    else if (gid < CSEG6) { s = wp;  d = bp;  l = gid - CSEG5; }
    else if (gid < CSEG7) { s = wsr; d = bsr; l = gid - CSEG6; }
    else return;
    float4 v = *(const float4*)(s + (size_t)l * 4);
    *(ushort4*)(d + (size_t)l * 4) =
        make_ushort4(f2bf(v.x), f2bf(v.y), f2bf(v.z), f2bf(v.w));
}

// ---------------------------------------------------------------------------
// bf16 MFMA GEMM: out[M,ldout] = (A [+ A2]) @ W^T [+ bias]
// A: [M,K] bf16, W: [ldout,K] bf16 (row-major).  128x128 tile, BK=32,
// 256 threads = 4 waves in 2x2, each wave 64x64 via 4x4 mfma 16x16x32 tiles.
// mode: 0 = bf16 out (+bias), 1 = fp32 out (+bias), 2 = fp32 atomicAdd
// split-K: kbeg = blockIdx.z * kLen.
// ---------------------------------------------------------------------------
#define LDA 40   // padded LDS row stride (bf16 elems): 20 dwords, 2-way free

__global__ __launch_bounds__(256) void gemm_bf16(
    const u16* __restrict__ A, const u16* __restrict__ A2,
    const u16* __restrict__ W, const float* __restrict__ bias,
    void* __restrict__ outp, int M, int K, int ldout, int kLen, int mode)
{
    __shared__ u16 Asm[128 * LDA];
    __shared__ u16 Bsm[128 * LDA];
    const int tid = threadIdx.x;
    const int m0 = blockIdx.x * 128;
    const int n0 = blockIdx.y * 128;
    const int kbeg = blockIdx.z * kLen;
    const int wave = tid >> 6, lane = tid & 63;
    const int wm = (wave & 1) * 64, wn = (wave >> 1) * 64;
    const int fr = lane & 15, fq = lane >> 4;

    v4f acc[4][4];
#pragma unroll
    for (int i = 0; i < 4; i++)
#pragma unroll
        for (int j = 0; j < 4; j++) acc[i][j] = (v4f){0.f, 0.f, 0.f, 0.f};

    for (int kk = kbeg; kk < kbeg + kLen; kk += 32) {
        // stage A tile (guarded rows) and W tile (rows always valid)
#pragma unroll
        for (int i = 0; i < 2; i++) {
            int u = tid + i * 256;           // 0..511
            int r = u >> 2, kc = (u & 3) * 8;
            uint4 av = make_uint4(0, 0, 0, 0);
            int m = m0 + r;
            if (m < M) {
                av = *(const uint4*)(A + (size_t)m * K + kk + kc);
                if (A2) {
                    uint4 bv = *(const uint4*)(A2 + (size_t)m * K + kk + kc);
                    av.x = bfadd2(av.x, bv.x); av.y = bfadd2(av.y, bv.y);
                    av.z = bfadd2(av.z, bv.z); av.w = bfadd2(av.w, bv.w);
                }
            }
            *(uint4*)(Asm + r * LDA + kc) = av;
            uint4 wv = *(const uint4*)(W + (size_t)(n0 + r) * K + kk + kc);
            *(uint4*)(Bsm + r * LDA + kc) = wv;
        }
        __syncthreads();

        v8s af[4], bfr[4];
#pragma unroll
        for (int i = 0; i < 4; i++)
            af[i] = *(const v8s*)(Asm + (wm + i * 16 + fr) * LDA + fq * 8);
#pragma unroll
        for (int j = 0; j < 4; j++)
            bfr[j] = *(const v8s*)(Bsm + (wn + j * 16 + fr) * LDA + fq * 8);
#pragma unroll
        for (int i = 0; i < 4; i++)
#pragma unroll
            for (int j = 0; j < 4; j++)
                acc[i][j] = __builtin_amdgcn_mfma_f32_16x16x32_bf16(
                    af[i], bfr[j], acc[i][j], 0, 0, 0);
        __syncthreads();
    }

    // epilogue: C/D layout col = lane&15, row = (lane>>4)*4 + reg
    float* outf = (float*)outp;
    u16*   outb = (u16*)outp;
#pragma unroll
    for (int i = 0; i < 4; i++) {
#pragma unroll
        for (int j = 0; j < 4; j++) {
            int col = n0 + wn + j * 16 + fr;
#pragma unroll
            for (int r = 0; r < 4; r++) {
                int row = m0 + wm + i * 16 + fq * 4 + r;
                if (row >= M) continue;
                float v = acc[i][j][r];
                if (mode == 2) {
                    atomicAdd(outf + (size_t)row * ldout + col, v);
                } else {
                    if (bias) v += bias[col];
                    if (mode == 0) outb[(size_t)row * ldout + col] = f2bf(v);
                    else           outf[(size_t)row * ldout + col] = v;
                }
            }
        }
    }
}

// ---------------------------------------------------------------------------
// im2col for stride-4 4x4x4 VALID conv -> bf16 out.
// out[p][ci*64 + tap] = x[n(p,tap)][ci]
// ---------------------------------------------------------------------------
__global__ __launch_bounds__(256) void im2col_kernel(
    const float* __restrict__ x, u16* __restrict__ out)
{
    int idx = blockIdx.x * 256 + threadIdx.x;    // exact grid: 343*16384
    int p   = idx >> 14;
    int k   = idx & 16383;
    int ci  = k >> 6;
    int tap = k & 63;
    int kz = tap >> 4, ky = (tap >> 2) & 3, kx = tap & 3;
    int pz = p / 49, pr = p % 49, py = pr / 7, px = pr % 7;
    int n = (pz * 4 + kz) * 784 + (py * 4 + ky) * 28 + (px * 4 + kx);
    out[idx] = f2bf(x[(size_t)n * 256 + ci]);
}

__global__ __launch_bounds__(256) void init_bias_kernel(
    const float* __restrict__ b, float* __restrict__ out)
{
    out[blockIdx.x * 256 + threadIdx.x] = b[threadIdx.x];
}

// ---------------------------------------------------------------------------
// Depthwise 3x3x3 SAME conv, LDS-tiled: block = (4^3 voxel tile, 64-ch group).
// grid (343, 4).  Halo 6x6x6 x 64ch staged as fp32 (55 KB), weights in LDS.
// input y bf16 [N,256], output lepe bf16 [N,256].
// ---------------------------------------------------------------------------
__global__ __launch_bounds__(256) void dwconv_kernel(
    const u16* __restrict__ y, const float* __restrict__ w,
    const float* __restrict__ bias, u16* __restrict__ out)
{
    __shared__ float sm[216 * 64];
    __shared__ float sw[64 * 27];
    const int tid = threadIdx.x;
    const int t  = blockIdx.x;
    const int g  = blockIdx.y;
    const int tz = t / 49, tr = t % 49, ty = tr / 7, tx = tr % 7;

    // stage weights for this channel group
    for (int u = tid; u < 64 * 27; u += 256) sw[u] = w[g * 64 * 27 + u];

    // stage halo volume: 216 voxels x 64 ch (8 bf16 per thread-iter)
    for (int u = tid; u < 216 * 8; u += 256) {
        int r = u >> 3, c8 = (u & 7) * 8;
        int vz = tz * 4 - 1 + r / 36;
        int rem = r % 36;
        int vy = ty * 4 - 1 + rem / 6;
        int vx = tx * 4 - 1 + rem % 6;
        float f[8];
        if ((unsigned)vz < 28u && (unsigned)vy < 28u && (unsigned)vx < 28u) {
            int n = vz * 784 + vy * 28 + vx;
            uint4 raw = *(const uint4*)(y + (size_t)n * 256 + g * 64 + c8);
            f[0] = bf2f(raw.x & 0xffffu); f[1] = bf2f(raw.x >> 16);
            f[2] = bf2f(raw.y & 0xffffu); f[3] = bf2f(raw.y >> 16);
            f[4] = bf2f(raw.z & 0xffffu); f[5] = bf2f(raw.z >> 16);
            f[6] = bf2f(raw.w & 0xffffu); f[7] = bf2f(raw.w >> 16);
        } else {
#pragma unroll
            for (int i = 0; i < 8; i++) f[i] = 0.f;
        }
        float* dst = &sm[r * 64 + c8];
        *(float4*)dst       = make_float4(f[0], f[1], f[2], f[3]);
        *(float4*)(dst + 4) = make_float4(f[4], f[5], f[6], f[7]);
    }
    __syncthreads();

    const int c  = tid & 63;
    const int ch = g * 64 + c;
    float wreg[27];
#pragma unroll
    for (int j = 0; j < 27; j++) wreg[j] = sw[c * 27 + j];
    const float bc = bias[ch];

    const int vbase = (tid >> 6) * 16;
    for (int v = vbase; v < vbase + 16; v++) {
        int vz = v >> 4, vy = (v >> 2) & 3, vx = v & 3;
        float a = bc;
#pragma unroll
        for (int dz = 0; dz < 3; dz++)
#pragma unroll
            for (int dy = 0; dy < 3; dy++)
#pragma unroll
                for (int dx = 0; dx < 3; dx++)
                    a = fmaf(sm[((vz + dz) * 36 + (vy + dy) * 6 + (vx + dx)) * 64 + c],
                             wreg[dz * 9 + dy * 3 + dx], a);
        int n = (tz * 4 + vz) * 784 + (ty * 4 + vy) * 28 + (tx * 4 + vx);
        out[(size_t)n * 256 + ch] = f2bf(a);
    }
}

// ---------------------------------------------------------------------------
// LayerNorm (C=256) + exact GELU. fp32 in, bf16 out. One block per row.
// ---------------------------------------------------------------------------
__global__ __launch_bounds__(256) void ln_gelu_kernel(
    const float* __restrict__ in, const float* __restrict__ g,
    const float* __restrict__ b, u16* __restrict__ out)
{
    int row = blockIdx.x, c = threadIdx.x;
    float v = in[row * 256 + c];
    float s = v, s2 = v * v;
#pragma unroll
    for (int off = 1; off < 64; off <<= 1) {
        s  += __shfl_xor(s,  off);
        s2 += __shfl_xor(s2, off);
    }
    __shared__ float ws[4], ws2[4];
    int wave = c >> 6, lane = c & 63;
    if (lane == 0) { ws[wave] = s; ws2[wave] = s2; }
    __syncthreads();
    float mean = (ws[0] + ws[1] + ws[2] + ws[3]) * (1.f / 256.f);
    float m2   = (ws2[0] + ws2[1] + ws2[2] + ws2[3]) * (1.f / 256.f);
    float var  = m2 - mean * mean;
    float xn = (v - mean) * rsqrtf(var + 1e-5f) * g[c] + b[c];
    out[row * 256 + c] = f2bf(0.5f * xn * (1.f + erff(xn * 0.70710678118654752f)));
}

// ---------------------------------------------------------------------------
// Branch 1 attention: one THREAD per query, K/V (bf16) staged to LDS as fp32.
// grid (86, 4).  q: [N,128] bf16; kv1: [343,256] bf16. o: bf16 cols 0..127.
// ---------------------------------------------------------------------------
__global__ __launch_bounds__(256) void attn1_kernel(
    const u16* __restrict__ q1, const u16* __restrict__ kv1,
    u16* __restrict__ o)
{
    __shared__ float Ks[KC * 32];
    __shared__ float Vs[KC * 32];
    const int tid = threadIdx.x;
    const int h = blockIdx.y;
    const int n = blockIdx.x * 256 + tid;
    const bool valid = (n < N_TOK);

    float qf[32];
#pragma unroll
    for (int i = 0; i < 32; i++) qf[i] = 0.f;
    if (valid) {
        const u16* qp = q1 + (size_t)n * 128 + h * 32;
#pragma unroll
        for (int i = 0; i < 4; i++) {
            uint4 r4 = *(const uint4*)(qp + i * 8);
            qf[i*8+0] = bf2f(r4.x & 0xffffu); qf[i*8+1] = bf2f(r4.x >> 16);
            qf[i*8+2] = bf2f(r4.y & 0xffffu); qf[i*8+3] = bf2f(r4.y >> 16);
            qf[i*8+4] = bf2f(r4.z & 0xffffu); qf[i*8+5] = bf2f(r4.z >> 16);
            qf[i*8+6] = bf2f(r4.w & 0xffffu); qf[i*8+7] = bf2f(r4.w >> 16);
        }
    }

    float mrun = -__builtin_inff(), lrun = 0.f;
    float acc[32];
#pragma unroll
    for (int d = 0; d < 32; d++) acc[d] = 0.f;

    for (int k0 = 0; k0 < NR; k0 += KC) {
        int cnt = min(KC, NR - k0);
        for (int u = tid; u < cnt * 8; u += 256) {
            int r = u >> 3, p = u & 7;
            int col = (p < 4) ? (h * 32 + p * 8) : (128 + h * 32 + (p - 4) * 8);
            uint4 r4 = *(const uint4*)(kv1 + (size_t)(k0 + r) * 256 + col);
            float* dst = ((p < 4) ? Ks : Vs) + r * 32 + (p & 3) * 8;
            dst[0] = bf2f(r4.x & 0xffffu); dst[1] = bf2f(r4.x >> 16);
            dst[2] = bf2f(r4.y & 0xffffu); dst[3] = bf2f(r4.y >> 16);
            dst[4] = bf2f(r4.z & 0xffffu); dst[5] = bf2f(r4.z >> 16);
            dst[6] = bf2f(r4.w & 0xffffu); dst[7] = bf2f(r4.w >> 16);
        }
        __syncthreads();
        for (int m = 0; m < cnt; m++) {
            const float* kp = &Ks[m * 32];
            float d0 = 0.f, d1 = 0.f, d2 = 0.f, d3 = 0.f;
#pragma unroll
            for (int i = 0; i < 8; i++) {
                d0 = fmaf(qf[i*4+0], kp[i*4+0], d0);
                d1 = fmaf(qf[i*4+1], kp[i*4+1], d1);
                d2 = fmaf(qf[i*4+2], kp[i*4+2], d2);
                d3 = fmaf(qf[i*4+3], kp[i*4+3], d3);
            }
            float s = ((d0 + d1) + (d2 + d3)) * ATT_SCALE;
            float p;
            if (s > mrun) {
                float alpha = __expf(mrun - s);   // first key: exp(-inf)=0
                mrun = s;
                lrun *= alpha;
#pragma unroll
                for (int d = 0; d < 32; d++) acc[d] *= alpha;
                p = 1.f;
            } else {
                p = __expf(s - mrun);
            }
            lrun += p;
            const float* vp = &Vs[m * 32];
#pragma unroll
            for (int d = 0; d < 32; d++) acc[d] = fmaf(p, vp[d], acc[d]);
        }
        __syncthreads();
    }

    if (valid) {
        float inv = 1.f / lrun;
        u16* op = o + (size_t)n * 256 + h * 32;
#pragma unroll
        for (int i = 0; i < 4; i++) {
            uint4 w4;
            w4.x = (unsigned)f2bf(acc[i*8+0]*inv) | ((unsigned)f2bf(acc[i*8+1]*inv) << 16);
            w4.y = (unsigned)f2bf(acc[i*8+2]*inv) | ((unsigned)f2bf(acc[i*8+3]*inv) << 16);
            w4.z = (unsigned)f2bf(acc[i*8+4]*inv) | ((unsigned)f2bf(acc[i*8+5]*inv) << 16);
            w4.w = (unsigned)f2bf(acc[i*8+6]*inv) | ((unsigned)f2bf(acc[i*8+7]*inv) << 16);
            *(uint4*)(op + i * 8) = w4;
        }
    }
}

// ---------------------------------------------------------------------------
// Branch 2 windowed attention: block per (window, head) = 256 blocks,
// 384 threads, one THREAD per query token of the 7^3 window.
// ---------------------------------------------------------------------------
__global__ __launch_bounds__(384) void attn2_kernel(
    const u16* __restrict__ q2, const u16* __restrict__ kv2,
    u16* __restrict__ o)
{
    __shared__ float Ks[KC * 32];
    __shared__ float Vs[KC * 32];
    const int tid = threadIdx.x;
    const int wi = blockIdx.x;
    const int h  = wi >> 6;
    const int zb = (wi >> 4) & 3, yb = (wi >> 2) & 3, xb = wi & 3;
    const bool valid = (tid < NR);

    int nq = 0;
    if (valid) {
        int wz = tid / 49, tr = tid % 49, wy = tr / 7, wx = tr % 7;
        nq = (zb * 7 + wz) * 784 + (yb * 7 + wy) * 28 + (xb * 7 + wx);
    }

    float qf[32];
#pragma unroll
    for (int i = 0; i < 32; i++) qf[i] = 0.f;
    if (valid) {
        const u16* qp = q2 + (size_t)nq * 128 + h * 32;
#pragma unroll
        for (int i = 0; i < 4; i++) {
            uint4 r4 = *(const uint4*)(qp + i * 8);
            qf[i*8+0] = bf2f(r4.x & 0xffffu); qf[i*8+1] = bf2f(r4.x >> 16);
            qf[i*8+2] = bf2f(r4.y & 0xffffu); qf[i*8+3] = bf2f(r4.y >> 16);
            qf[i*8+4] = bf2f(r4.z & 0xffffu); qf[i*8+5] = bf2f(r4.z >> 16);
            qf[i*8+6] = bf2f(r4.w & 0xffffu); qf[i*8+7] = bf2f(r4.w >> 16);
        }
    }

    float mrun = -__builtin_inff(), lrun = 0.f;
    float acc[32];
#pragma unroll
    for (int d = 0; d < 32; d++) acc[d] = 0.f;

    for (int k0 = 0; k0 < NR; k0 += KC) {
        int cnt = min(KC, NR - k0);
        for (int u = tid; u < cnt * 8; u += 384) {
            int r = u >> 3, p = u & 7;
            int m = k0 + r;
            int mz = m / 49, mr = m % 49, my = mr / 7, mx = mr % 7;
            int nk = (zb * 7 + mz) * 784 + (yb * 7 + my) * 28 + (xb * 7 + mx);
            int col = (p < 4) ? (h * 32 + p * 8) : (128 + h * 32 + (p - 4) * 8);
            uint4 r4 = *(const uint4*)(kv2 + (size_t)nk * 256 + col);
            float* dst = ((p < 4) ? Ks : Vs) + r * 32 + (p & 3) * 8;
            dst[0] = bf2f(r4.x & 0xffffu); dst[1] = bf2f(r4.x >> 16);
            dst[2] = bf2f(r4.y & 0xffffu); dst[3] = bf2f(r4.y >> 16);
            dst[4] = bf2f(r4.z & 0xffffu); dst[5] = bf2f(r4.z >> 16);
            dst[6] = bf2f(r4.w & 0xffffu); dst[7] = bf2f(r4.w >> 16);
        }
        __syncthreads();
        for (int m = 0; m < cnt; m++) {
            const float* kp = &Ks[m * 32];
            float d0 = 0.f, d1 = 0.f, d2 = 0.f, d3 = 0.f;
#pragma unroll
            for (int i = 0; i < 8; i++) {
                d0 = fmaf(qf[i*4+0], kp[i*4+0], d0);
                d1 = fmaf(qf[i*4+1], kp[i*4+1], d1);
                d2 = fmaf(qf[i*4+2], kp[i*4+2], d2);
                d3 = fmaf(qf[i*4+3], kp[i*4+3], d3);
            }
            float s = ((d0 + d1) + (d2 + d3)) * ATT_SCALE;
            float p;
            if (s > mrun) {
                float alpha = __expf(mrun - s);
                mrun = s;
                lrun *= alpha;
#pragma unroll
                for (int d = 0; d < 32; d++) acc[d] *= alpha;
                p = 1.f;
            } else {
                p = __expf(s - mrun);
            }
            lrun += p;
            const float* vp = &Vs[m * 32];
#pragma unroll
            for (int d = 0; d < 32; d++) acc[d] = fmaf(p, vp[d], acc[d]);
        }
        __syncthreads();
    }

    if (valid) {
        float inv = 1.f / lrun;
        u16* op = o + (size_t)nq * 256 + 128 + h * 32;
#pragma unroll
        for (int i = 0; i < 4; i++) {
            uint4 w4;
            w4.x = (unsigned)f2bf(acc[i*8+0]*inv) | ((unsigned)f2bf(acc[i*8+1]*inv) << 16);
            w4.y = (unsigned)f2bf(acc[i*8+2]*inv) | ((unsigned)f2bf(acc[i*8+3]*inv) << 16);
            w4.z = (unsigned)f2bf(acc[i*8+4]*inv) | ((unsigned)f2bf(acc[i*8+5]*inv) << 16);
            w4.w = (unsigned)f2bf(acc[i*8+6]*inv) | ((unsigned)f2bf(acc[i*8+7]*inv) << 16);
            *(uint4*)(op + i * 8) = w4;
        }
    }
}

// ---------------------------------------------------------------------------
extern "C" void kernel_launch(void* const* d_in, const int* in_sizes, int n_in,
                              void* d_out, int out_size, void* d_ws, size_t ws_size,
                              hipStream_t stream)
{
    const float* x       = (const float*)d_in[0];
    const float* lepe_w  = (const float*)d_in[4];
    const float* lepe_b  = (const float*)d_in[5];
    const float* lconv_w = (const float*)d_in[6];
    const float* lconv_b = (const float*)d_in[7];
    const float* sr_w    = (const float*)d_in[8];
    const float* sr_b    = (const float*)d_in[9];
    const float* norm_g  = (const float*)d_in[10];
    const float* norm_b  = (const float*)d_in[11];
    const float* q1_w    = (const float*)d_in[12];
    const float* kv1_w   = (const float*)d_in[13];
    const float* q2_w    = (const float*)d_in[14];
    const float* kv2_w   = (const float*)d_in[15];
    const float* proj_w  = (const float*)d_in[16];
    const float* proj_b  = (const float*)d_in[17];
    float* out = (float*)d_out;

    const size_t NC  = (size_t)N_TOK * 256;   // 5,619,712
    const size_t NC2 = (size_t)N_TOK * 128;

    float* srout = (float*)d_ws;              // [343,256] fp32
    u16* base = (u16*)(srout + NR * 256);
    u16* xb      = base;                      // bf16(x)           [N,256]
    u16* yb      = xb + NC;                   // lepe linear; later kv2
    u16* lepeb   = yb + NC;                   // lepe conv out
    u16* colb    = lepeb + NC;                // im2col; later o (concat)
    u16* qb      = colb + NC;                 // q1, later q2      [N,128]
    u16* x1b     = qb + NC2;                  // [343,256]
    u16* kv1b    = x1b + NR * 256;            // [343,256]
    u16* wb_l    = kv1b + NR * 256;           // weights bf16
    u16* wb_q1   = wb_l  + 65536;
    u16* wb_q2   = wb_q1 + 32768;
    u16* wb_k1   = wb_q2 + 32768;
    u16* wb_k2   = wb_k1 + 65536;
    u16* wb_p    = wb_k2 + 65536;
    u16* wb_sr   = wb_p  + 65536;             // [256,16384]
    size_t need = (size_t)NR * 256 * 4 +
                  (4 * NC + NC2 + 2 * (size_t)NR * 256 +
                   65536 * 5 + 32768 * 2 + 4194304) * 2;
    if (ws_size < need) return;

    // 0. fp32 -> bf16 for x and all weights
    convert_all_kernel<<<dim3(9904), 256, 0, stream>>>(
        x, lepe_w, q1_w, q2_w, kv1_w, kv2_w, proj_w, sr_w,
        xb, wb_l, wb_q1, wb_q2, wb_k1, wb_k2, wb_p, wb_sr);
    // 1. y = x @ lepe_w^T + lepe_b   (bf16 out)
    gemm_bf16<<<dim3(172, 2), 256, 0, stream>>>(xb, nullptr, wb_l, lepe_b,
                                                yb, N_TOK, 256, 256, 256, 0);
    // 2. lepe = depthwise conv(y)
    dwconv_kernel<<<dim3(343, 4), 256, 0, stream>>>(yb, lconv_w, lconv_b, lepeb);
    // 3. im2col of x (bf16 out)
    im2col_kernel<<<dim3(21952), 256, 0, stream>>>(x, colb);
    // 4. srout = bias; split-K MFMA GEMM accumulates (fp32 atomics)
    init_bias_kernel<<<dim3(NR), 256, 0, stream>>>(sr_b, srout);
    gemm_bf16<<<dim3(3, 2, 8), 256, 0, stream>>>(colb, nullptr, wb_sr, nullptr,
                                                 srout, NR, 16384, 256, 2048, 2);
    // 5. x1 = gelu(layernorm(srout))  (bf16 out)
    ln_gelu_kernel<<<dim3(NR), 256, 0, stream>>>(srout, norm_g, norm_b, x1b);
    // 6. kv1 = x1 @ kv1_w^T
    gemm_bf16<<<dim3(3, 2), 256, 0, stream>>>(x1b, nullptr, wb_k1, nullptr,
                                              kv1b, NR, 256, 256, 256, 0);
    // 7. q1 = x @ q1_w^T
    gemm_bf16<<<dim3(172, 1), 256, 0, stream>>>(xb, nullptr, wb_q1, nullptr,
                                                qb, N_TOK, 256, 128, 256, 0);
    // 8. branch-1 attention -> o[:, :128]   (colb free, reused as o)
    attn1_kernel<<<dim3(86, 4), 256, 0, stream>>>(qb, kv1b, colb);
    // 9. q2 = x @ q2_w^T
    gemm_bf16<<<dim3(172, 1), 256, 0, stream>>>(xb, nullptr, wb_q2, nullptr,
                                                qb, N_TOK, 256, 128, 256, 0);
    // 10. kv2 = x @ kv2_w^T  (yb free, reused)
    gemm_bf16<<<dim3(172, 2), 256, 0, stream>>>(xb, nullptr, wb_k2, nullptr,
                                                yb, N_TOK, 256, 256, 256, 0);
    // 11. branch-2 windowed attention -> o[:, 128:]
    attn2_kernel<<<dim3(256), 384, 0, stream>>>(qb, yb, colb);
    // 12. out = (o + lepe) @ proj_w^T + proj_b  (fp32 out)
    gemm_bf16<<<dim3(172, 2), 256, 0, stream>>>(colb, lepeb, wb_p, proj_b,
                                                out, N_TOK, 256, 256, 256, 1);
}

// Round 4
// 393.269 us; speedup vs baseline: 6.8432x; 1.7433x over previous
//
#include <hip/hip_runtime.h>

#define N_TOK 21952          // 28*28*28
#define NR    343            // 7*7*7
#define ATT_SCALE 0.17677669529663687f   // 32^-0.5

typedef unsigned short u16;
typedef short  v8s __attribute__((ext_vector_type(8)));
typedef float  v4f __attribute__((ext_vector_type(4)));

__device__ __forceinline__ float bf2f(unsigned u) {
    return __builtin_bit_cast(float, u << 16);
}
__device__ __forceinline__ u16 f2bf(float f) {
    unsigned u = __builtin_bit_cast(unsigned, f);
    u += 0x7fffu + ((u >> 16) & 1u);
    return (u16)(u >> 16);
}
__device__ __forceinline__ unsigned bfadd2(unsigned a, unsigned b) {
    float lo = bf2f(a & 0xffffu) + bf2f(b & 0xffffu);
    float hi = bf2f(a >> 16)     + bf2f(b >> 16);
    return (unsigned)f2bf(lo) | ((unsigned)f2bf(hi) << 16);
}

// ---------------------------------------------------------------------------
// Fused fp32 -> bf16 conversion of x + 7 weight tensors. One float4 / thread.
// q1_w / q2_w are pre-scaled by ATT_SCALE (folded out of the attention).
// ---------------------------------------------------------------------------
#define CSEG0 1404928   // x        (5619712/4)
#define CSEG1 1421312   // + lepe_w (65536/4)
#define CSEG2 1429504   // + q1_w   (32768/4)
#define CSEG3 1437696   // + q2_w
#define CSEG4 1454080   // + kv1_w  (65536/4)
#define CSEG5 1470464   // + kv2_w
#define CSEG6 1486848   // + proj_w
#define CSEG7 2535424   // + sr_w   (4194304/4)

__global__ __launch_bounds__(256) void convert_all_kernel(
    const float* __restrict__ x,   const float* __restrict__ wl,
    const float* __restrict__ wq1, const float* __restrict__ wq2,
    const float* __restrict__ wk1, const float* __restrict__ wk2,
    const float* __restrict__ wp,  const float* __restrict__ wsr,
    u16* xb, u16* bl, u16* bq1, u16* bq2, u16* bk1, u16* bk2, u16* bp, u16* bsr)
{
    int gid = blockIdx.x * 256 + threadIdx.x;
    const float* s; u16* d; int l; float sc = 1.f;
    if      (gid < CSEG0) { s = x;   d = xb;  l = gid; }
    else if (gid < CSEG1) { s = wl;  d = bl;  l = gid - CSEG0; }
    else if (gid < CSEG2) { s = wq1; d = bq1; l = gid - CSEG1; sc = ATT_SCALE; }
    else if (gid < CSEG3) { s = wq2; d = bq2; l = gid - CSEG2; sc = ATT_SCALE; }
    else if (gid < CSEG4) { s = wk1; d = bk1; l = gid - CSEG3; }
    else if (gid < CSEG5) { s = wk2; d = bk2; l = gid - CSEG4; }
    else if (gid < CSEG6) { s = wp;  d = bp;  l = gid - CSEG5; }
    else if (gid < CSEG7) { s = wsr; d = bsr; l = gid - CSEG6; }
    else return;
    float4 v = *(const float4*)(s + (size_t)l * 4);
    *(ushort4*)(d + (size_t)l * 4) =
        make_ushort4(f2bf(v.x * sc), f2bf(v.y * sc), f2bf(v.z * sc), f2bf(v.w * sc));
}

// ---------------------------------------------------------------------------
// bf16 MFMA GEMM: out[M,ldout] = (A [+ A2]) @ W^T [+ bias]
// 128x128 tile, BK=32, 4 waves (2x2), 4x4 mfma 16x16x32 per wave.
// mode: 0 = bf16 out (+bias), 1 = fp32 out (+bias), 2 = fp32 atomicAdd
// ---------------------------------------------------------------------------
#define LDA 40   // padded LDS row stride (bf16 elems)

__global__ __launch_bounds__(256) void gemm_bf16(
    const u16* __restrict__ A, const u16* __restrict__ A2,
    const u16* __restrict__ W, const float* __restrict__ bias,
    void* __restrict__ outp, int M, int K, int ldout, int kLen, int mode)
{
    __shared__ u16 Asm[128 * LDA];
    __shared__ u16 Bsm[128 * LDA];
    const int tid = threadIdx.x;
    const int m0 = blockIdx.x * 128;
    const int n0 = blockIdx.y * 128;
    const int kbeg = blockIdx.z * kLen;
    const int wave = tid >> 6, lane = tid & 63;
    const int wm = (wave & 1) * 64, wn = (wave >> 1) * 64;
    const int fr = lane & 15, fq = lane >> 4;

    v4f acc[4][4];
#pragma unroll
    for (int i = 0; i < 4; i++)
#pragma unroll
        for (int j = 0; j < 4; j++) acc[i][j] = (v4f){0.f, 0.f, 0.f, 0.f};

    for (int kk = kbeg; kk < kbeg + kLen; kk += 32) {
#pragma unroll
        for (int i = 0; i < 2; i++) {
            int u = tid + i * 256;           // 0..511
            int r = u >> 2, kc = (u & 3) * 8;
            uint4 av = make_uint4(0, 0, 0, 0);
            int m = m0 + r;
            if (m < M) {
                av = *(const uint4*)(A + (size_t)m * K + kk + kc);
                if (A2) {
                    uint4 bv = *(const uint4*)(A2 + (size_t)m * K + kk + kc);
                    av.x = bfadd2(av.x, bv.x); av.y = bfadd2(av.y, bv.y);
                    av.z = bfadd2(av.z, bv.z); av.w = bfadd2(av.w, bv.w);
                }
            }
            *(uint4*)(Asm + r * LDA + kc) = av;
            uint4 wv = *(const uint4*)(W + (size_t)(n0 + r) * K + kk + kc);
            *(uint4*)(Bsm + r * LDA + kc) = wv;
        }
        __syncthreads();

        v8s af[4], bfr[4];
#pragma unroll
        for (int i = 0; i < 4; i++)
            af[i] = *(const v8s*)(Asm + (wm + i * 16 + fr) * LDA + fq * 8);
#pragma unroll
        for (int j = 0; j < 4; j++)
            bfr[j] = *(const v8s*)(Bsm + (wn + j * 16 + fr) * LDA + fq * 8);
#pragma unroll
        for (int i = 0; i < 4; i++)
#pragma unroll
            for (int j = 0; j < 4; j++)
                acc[i][j] = __builtin_amdgcn_mfma_f32_16x16x32_bf16(
                    af[i], bfr[j], acc[i][j], 0, 0, 0);
        __syncthreads();
    }

    float* outf = (float*)outp;
    u16*   outb = (u16*)outp;
#pragma unroll
    for (int i = 0; i < 4; i++) {
#pragma unroll
        for (int j = 0; j < 4; j++) {
            int col = n0 + wn + j * 16 + fr;
#pragma unroll
            for (int r = 0; r < 4; r++) {
                int row = m0 + wm + i * 16 + fq * 4 + r;
                if (row >= M) continue;
                float v = acc[i][j][r];
                if (mode == 2) {
                    atomicAdd(outf + (size_t)row * ldout + col, v);
                } else {
                    if (bias) v += bias[col];
                    if (mode == 0) outb[(size_t)row * ldout + col] = f2bf(v);
                    else           outf[(size_t)row * ldout + col] = v;
                }
            }
        }
    }
}

// ---------------------------------------------------------------------------
// im2col for stride-4 4x4x4 VALID conv -> bf16 out.
// ---------------------------------------------------------------------------
__global__ __launch_bounds__(256) void im2col_kernel(
    const float* __restrict__ x, u16* __restrict__ out)
{
    int idx = blockIdx.x * 256 + threadIdx.x;    // exact grid: 343*16384
    int p   = idx >> 14;
    int k   = idx & 16383;
    int ci  = k >> 6;
    int tap = k & 63;
    int kz = tap >> 4, ky = (tap >> 2) & 3, kx = tap & 3;
    int pz = p / 49, pr = p % 49, py = pr / 7, px = pr % 7;
    int n = (pz * 4 + kz) * 784 + (py * 4 + ky) * 28 + (px * 4 + kx);
    out[idx] = f2bf(x[(size_t)n * 256 + ci]);
}

__global__ __launch_bounds__(256) void init_bias_kernel(
    const float* __restrict__ b, float* __restrict__ out)
{
    out[blockIdx.x * 256 + threadIdx.x] = b[threadIdx.x];
}

// ---------------------------------------------------------------------------
// Depthwise 3x3x3 SAME conv, LDS-tiled (unchanged from round 3).
// ---------------------------------------------------------------------------
__global__ __launch_bounds__(256) void dwconv_kernel(
    const u16* __restrict__ y, const float* __restrict__ w,
    const float* __restrict__ bias, u16* __restrict__ out)
{
    __shared__ float sm[216 * 64];
    __shared__ float sw[64 * 27];
    const int tid = threadIdx.x;
    const int t  = blockIdx.x;
    const int g  = blockIdx.y;
    const int tz = t / 49, tr = t % 49, ty = tr / 7, tx = tr % 7;

    for (int u = tid; u < 64 * 27; u += 256) sw[u] = w[g * 64 * 27 + u];

    for (int u = tid; u < 216 * 8; u += 256) {
        int r = u >> 3, c8 = (u & 7) * 8;
        int vz = tz * 4 - 1 + r / 36;
        int rem = r % 36;
        int vy = ty * 4 - 1 + rem / 6;
        int vx = tx * 4 - 1 + rem % 6;
        float f[8];
        if ((unsigned)vz < 28u && (unsigned)vy < 28u && (unsigned)vx < 28u) {
            int n = vz * 784 + vy * 28 + vx;
            uint4 raw = *(const uint4*)(y + (size_t)n * 256 + g * 64 + c8);
            f[0] = bf2f(raw.x & 0xffffu); f[1] = bf2f(raw.x >> 16);
            f[2] = bf2f(raw.y & 0xffffu); f[3] = bf2f(raw.y >> 16);
            f[4] = bf2f(raw.z & 0xffffu); f[5] = bf2f(raw.z >> 16);
            f[6] = bf2f(raw.w & 0xffffu); f[7] = bf2f(raw.w >> 16);
        } else {
#pragma unroll
            for (int i = 0; i < 8; i++) f[i] = 0.f;
        }
        float* dst = &sm[r * 64 + c8];
        *(float4*)dst       = make_float4(f[0], f[1], f[2], f[3]);
        *(float4*)(dst + 4) = make_float4(f[4], f[5], f[6], f[7]);
    }
    __syncthreads();

    const int c  = tid & 63;
    const int ch = g * 64 + c;
    float wreg[27];
#pragma unroll
    for (int j = 0; j < 27; j++) wreg[j] = sw[c * 27 + j];
    const float bc = bias[ch];

    const int vbase = (tid >> 6) * 16;
    for (int v = vbase; v < vbase + 16; v++) {
        int vz = v >> 4, vy = (v >> 2) & 3, vx = v & 3;
        float a = bc;
#pragma unroll
        for (int dz = 0; dz < 3; dz++)
#pragma unroll
            for (int dy = 0; dy < 3; dy++)
#pragma unroll
                for (int dx = 0; dx < 3; dx++)
                    a = fmaf(sm[((vz + dz) * 36 + (vy + dy) * 6 + (vx + dx)) * 64 + c],
                             wreg[dz * 9 + dy * 3 + dx], a);
        int n = (tz * 4 + vz) * 784 + (ty * 4 + vy) * 28 + (tx * 4 + vx);
        out[(size_t)n * 256 + ch] = f2bf(a);
    }
}

// ---------------------------------------------------------------------------
// LayerNorm (C=256) + exact GELU. fp32 in, bf16 out.
// ---------------------------------------------------------------------------
__global__ __launch_bounds__(256) void ln_gelu_kernel(
    const float* __restrict__ in, const float* __restrict__ g,
    const float* __restrict__ b, u16* __restrict__ out)
{
    int row = blockIdx.x, c = threadIdx.x;
    float v = in[row * 256 + c];
    float s = v, s2 = v * v;
#pragma unroll
    for (int off = 1; off < 64; off <<= 1) {
        s  += __shfl_xor(s,  off);
        s2 += __shfl_xor(s2, off);
    }
    __shared__ float ws[4], ws2[4];
    int wave = c >> 6, lane = c & 63;
    if (lane == 0) { ws[wave] = s; ws2[wave] = s2; }
    __syncthreads();
    float mean = (ws[0] + ws[1] + ws[2] + ws[3]) * (1.f / 256.f);
    float m2   = (ws2[0] + ws2[1] + ws2[2] + ws2[3]) * (1.f / 256.f);
    float var  = m2 - mean * mean;
    float xn = (v - mean) * rsqrtf(var + 1e-5f) * g[c] + b[c];
    out[row * 256 + c] = f2bf(0.5f * xn * (1.f + erff(xn * 0.70710678118654752f)));
}

// ===========================================================================
// MFMA attention.  Operand conventions (HW-validated by gemm_bf16 above):
//   A-frag: lane holds A[m = lane&15][k = (lane>>4)*8 + j], j=0..7
//   B-frag: lane holds W[n = lane&15][k = (lane>>4)*8 + j]   (W[n][k]=B[k][n])
//   C/D   : lane&15 = col(N), (lane>>4)*4 + reg = row(M)
// Block = (352-query tile, head). 4 waves; wave handles m-tiles mt = wave+4i.
// S row (22 key-tiles) kept in 88 VGPRs; exact 2-pass softmax; P goes
// through a 1.25 KB per-wave LDS buffer per 32-key chunk into PV MFMAs.
// Scale is pre-folded into q weights.  o: bf16 [N,256].
// ===========================================================================
#define KP  40    // K LDS row stride (bf16)
#define VTP 360   // V^T LDS row stride (bf16)
#define PP  40    // P LDS row stride (bf16)

__global__ __launch_bounds__(256) void attn1_kernel(
    const u16* __restrict__ q1, const u16* __restrict__ kv1,
    u16* __restrict__ o)
{
    __shared__ u16 Ks[352 * KP];
    __shared__ u16 VTs[32 * VTP];
    __shared__ u16 Ps[4 * 16 * PP];
    const int tid = threadIdx.x;
    const int h = blockIdx.y;
    const int qbase = blockIdx.x * 352;
    const int wave = tid >> 6, lane = tid & 63;
    const int fr = lane & 15, fq = lane >> 4;

    // ---- stage K [352][32] and V^T [32][352] (bf16, zero-padded) ----
    for (int u = tid; u < 352 * 4; u += 256) {
        int r = u >> 2, seg = u & 3;
        uint4 kq = make_uint4(0, 0, 0, 0), vq = make_uint4(0, 0, 0, 0);
        if (r < NR) {
            kq = *(const uint4*)(kv1 + (size_t)r * 256 + h * 32 + seg * 8);
            vq = *(const uint4*)(kv1 + (size_t)r * 256 + 128 + h * 32 + seg * 8);
        }
        *(uint4*)(Ks + r * KP + seg * 8) = kq;
        int d0 = seg * 8;
        VTs[(d0 + 0) * VTP + r] = (u16)(vq.x & 0xffffu);
        VTs[(d0 + 1) * VTP + r] = (u16)(vq.x >> 16);
        VTs[(d0 + 2) * VTP + r] = (u16)(vq.y & 0xffffu);
        VTs[(d0 + 3) * VTP + r] = (u16)(vq.y >> 16);
        VTs[(d0 + 4) * VTP + r] = (u16)(vq.z & 0xffffu);
        VTs[(d0 + 5) * VTP + r] = (u16)(vq.z >> 16);
        VTs[(d0 + 6) * VTP + r] = (u16)(vq.w & 0xffffu);
        VTs[(d0 + 7) * VTP + r] = (u16)(vq.w >> 16);
    }
    __syncthreads();

    u16* Pw = Ps + wave * 16 * PP;
    for (int mt = wave; mt < 22; mt += 4) {
        // Q A-frag straight from global
        int qrow = qbase + mt * 16 + fr;
        v8s aq = {0, 0, 0, 0, 0, 0, 0, 0};
        if (qrow < N_TOK)
            aq = *(const v8s*)(q1 + (size_t)qrow * 128 + h * 32 + fq * 8);

        // ---- S = Q K^T, full 352-key row in registers ----
        v4f s[22];
#pragma unroll
        for (int t = 0; t < 22; t++) {
            v8s bk = *(const v8s*)(Ks + (t * 16 + fr) * KP + fq * 8);
            s[t] = __builtin_amdgcn_mfma_f32_16x16x32_bf16(
                aq, bk, (v4f){0.f, 0.f, 0.f, 0.f}, 0, 0, 0);
        }
        if (fr >= 7) {           // keys 336+fr >= 343 invalid
#pragma unroll
            for (int r = 0; r < 4; r++) s[21][r] = -1e30f;
        }

        // ---- exact softmax (rows = fq*4+r, reduce over lane&15) ----
        float inv_l[4];
#pragma unroll
        for (int r = 0; r < 4; r++) {
            float m = s[0][r];
#pragma unroll
            for (int t = 1; t < 22; t++) m = fmaxf(m, s[t][r]);
#pragma unroll
            for (int off = 1; off < 16; off <<= 1) m = fmaxf(m, __shfl_xor(m, off));
            float l = 0.f;
#pragma unroll
            for (int t = 0; t < 22; t++) {
                v4f sv = s[t];
                float p = __expf(sv[r] - m);
                sv[r] = p; s[t] = sv;
                l += p;
            }
#pragma unroll
            for (int off = 1; off < 16; off <<= 1) l += __shfl_xor(l, off);
            inv_l[r] = 1.f / l;
        }

        // ---- O = P V via per-wave LDS chunks of 32 keys ----
        v4f o0 = {0.f, 0.f, 0.f, 0.f}, o1 = {0.f, 0.f, 0.f, 0.f};
#pragma unroll
        for (int kt = 0; kt < 11; kt++) {
#pragma unroll
            for (int tt = 0; tt < 2; tt++) {
                int t = kt * 2 + tt;
#pragma unroll
                for (int r = 0; r < 4; r++)
                    Pw[(fq * 4 + r) * PP + tt * 16 + fr] = f2bf(s[t][r]);
            }
            __asm__ volatile("s_waitcnt lgkmcnt(0)" ::: "memory");
            v8s ap  = *(const v8s*)(Pw + fr * PP + fq * 8);
            v8s bv0 = *(const v8s*)(VTs + fr * VTP + kt * 32 + fq * 8);
            v8s bv1 = *(const v8s*)(VTs + (16 + fr) * VTP + kt * 32 + fq * 8);
            o0 = __builtin_amdgcn_mfma_f32_16x16x32_bf16(ap, bv0, o0, 0, 0, 0);
            o1 = __builtin_amdgcn_mfma_f32_16x16x32_bf16(ap, bv1, o1, 0, 0, 0);
        }

        // ---- store (rows = fq*4+r, col = d = fr / 16+fr) ----
#pragma unroll
        for (int r = 0; r < 4; r++) {
            int n = qbase + mt * 16 + fq * 4 + r;
            if (n < N_TOK) {
                u16* op = o + (size_t)n * 256 + h * 32;
                op[fr]      = f2bf(o0[r] * inv_l[r]);
                op[16 + fr] = f2bf(o1[r] * inv_l[r]);
            }
        }
    }
}

__global__ __launch_bounds__(256) void attn2_kernel(
    const u16* __restrict__ q2, const u16* __restrict__ kv2,
    u16* __restrict__ o)
{
    __shared__ u16 Ks[352 * KP];
    __shared__ u16 VTs[32 * VTP];
    __shared__ u16 Ps[4 * 16 * PP];
    const int tid = threadIdx.x;
    const int h  = blockIdx.y;
    const int wi = blockIdx.x;
    const int zb = (wi >> 4) & 3, yb = (wi >> 2) & 3, xb = wi & 3;
    const int wave = tid >> 6, lane = tid & 63;
    const int fr = lane & 15, fq = lane >> 4;

    // ---- stage K / V^T for this window ----
    for (int u = tid; u < 352 * 4; u += 256) {
        int r = u >> 2, seg = u & 3;
        uint4 kq = make_uint4(0, 0, 0, 0), vq = make_uint4(0, 0, 0, 0);
        if (r < NR) {
            int mz = r / 49, mr = r % 49, my = mr / 7, mx = mr % 7;
            int nk = (zb * 7 + mz) * 784 + (yb * 7 + my) * 28 + (xb * 7 + mx);
            kq = *(const uint4*)(kv2 + (size_t)nk * 256 + h * 32 + seg * 8);
            vq = *(const uint4*)(kv2 + (size_t)nk * 256 + 128 + h * 32 + seg * 8);
        }
        *(uint4*)(Ks + r * KP + seg * 8) = kq;
        int d0 = seg * 8;
        VTs[(d0 + 0) * VTP + r] = (u16)(vq.x & 0xffffu);
        VTs[(d0 + 1) * VTP + r] = (u16)(vq.x >> 16);
        VTs[(d0 + 2) * VTP + r] = (u16)(vq.y & 0xffffu);
        VTs[(d0 + 3) * VTP + r] = (u16)(vq.y >> 16);
        VTs[(d0 + 4) * VTP + r] = (u16)(vq.z & 0xffffu);
        VTs[(d0 + 5) * VTP + r] = (u16)(vq.z >> 16);
        VTs[(d0 + 6) * VTP + r] = (u16)(vq.w & 0xffffu);
        VTs[(d0 + 7) * VTP + r] = (u16)(vq.w >> 16);
    }
    __syncthreads();

    u16* Pw = Ps + wave * 16 * PP;
    for (int mt = wave; mt < 22; mt += 4) {
        // Q A-frag from global via window token mapping
        int tw = mt * 16 + fr;
        v8s aq = {0, 0, 0, 0, 0, 0, 0, 0};
        if (tw < NR) {
            int wz = tw / 49, tr2 = tw % 49, wy = tr2 / 7, wx = tr2 % 7;
            int nq = (zb * 7 + wz) * 784 + (yb * 7 + wy) * 28 + (xb * 7 + wx);
            aq = *(const v8s*)(q2 + (size_t)nq * 128 + h * 32 + fq * 8);
        }

        v4f s[22];
#pragma unroll
        for (int t = 0; t < 22; t++) {
            v8s bk = *(const v8s*)(Ks + (t * 16 + fr) * KP + fq * 8);
            s[t] = __builtin_amdgcn_mfma_f32_16x16x32_bf16(
                aq, bk, (v4f){0.f, 0.f, 0.f, 0.f}, 0, 0, 0);
        }
        if (fr >= 7) {
#pragma unroll
            for (int r = 0; r < 4; r++) s[21][r] = -1e30f;
        }

        float inv_l[4];
#pragma unroll
        for (int r = 0; r < 4; r++) {
            float m = s[0][r];
#pragma unroll
            for (int t = 1; t < 22; t++) m = fmaxf(m, s[t][r]);
#pragma unroll
            for (int off = 1; off < 16; off <<= 1) m = fmaxf(m, __shfl_xor(m, off));
            float l = 0.f;
#pragma unroll
            for (int t = 0; t < 22; t++) {
                v4f sv = s[t];
                float p = __expf(sv[r] - m);
                sv[r] = p; s[t] = sv;
                l += p;
            }
#pragma unroll
            for (int off = 1; off < 16; off <<= 1) l += __shfl_xor(l, off);
            inv_l[r] = 1.f / l;
        }

        v4f o0 = {0.f, 0.f, 0.f, 0.f}, o1 = {0.f, 0.f, 0.f, 0.f};
#pragma unroll
        for (int kt = 0; kt < 11; kt++) {
#pragma unroll
            for (int tt = 0; tt < 2; tt++) {
                int t = kt * 2 + tt;
#pragma unroll
                for (int r = 0; r < 4; r++)
                    Pw[(fq * 4 + r) * PP + tt * 16 + fr] = f2bf(s[t][r]);
            }
            __asm__ volatile("s_waitcnt lgkmcnt(0)" ::: "memory");
            v8s ap  = *(const v8s*)(Pw + fr * PP + fq * 8);
            v8s bv0 = *(const v8s*)(VTs + fr * VTP + kt * 32 + fq * 8);
            v8s bv1 = *(const v8s*)(VTs + (16 + fr) * VTP + kt * 32 + fq * 8);
            o0 = __builtin_amdgcn_mfma_f32_16x16x32_bf16(ap, bv0, o0, 0, 0, 0);
            o1 = __builtin_amdgcn_mfma_f32_16x16x32_bf16(ap, bv1, o1, 0, 0, 0);
        }

#pragma unroll
        for (int r = 0; r < 4; r++) {
            int ts = mt * 16 + fq * 4 + r;
            if (ts < NR) {
                int wz = ts / 49, tr2 = ts % 49, wy = tr2 / 7, wx = tr2 % 7;
                int nq = (zb * 7 + wz) * 784 + (yb * 7 + wy) * 28 + (xb * 7 + wx);
                u16* op = o + (size_t)nq * 256 + 128 + h * 32;
                op[fr]      = f2bf(o0[r] * inv_l[r]);
                op[16 + fr] = f2bf(o1[r] * inv_l[r]);
            }
        }
    }
}

// ---------------------------------------------------------------------------
extern "C" void kernel_launch(void* const* d_in, const int* in_sizes, int n_in,
                              void* d_out, int out_size, void* d_ws, size_t ws_size,
                              hipStream_t stream)
{
    const float* x       = (const float*)d_in[0];
    const float* lepe_w  = (const float*)d_in[4];
    const float* lepe_b  = (const float*)d_in[5];
    const float* lconv_w = (const float*)d_in[6];
    const float* lconv_b = (const float*)d_in[7];
    const float* sr_w    = (const float*)d_in[8];
    const float* sr_b    = (const float*)d_in[9];
    const float* norm_g  = (const float*)d_in[10];
    const float* norm_b  = (const float*)d_in[11];
    const float* q1_w    = (const float*)d_in[12];
    const float* kv1_w   = (const float*)d_in[13];
    const float* q2_w    = (const float*)d_in[14];
    const float* kv2_w   = (const float*)d_in[15];
    const float* proj_w  = (const float*)d_in[16];
    const float* proj_b  = (const float*)d_in[17];
    float* out = (float*)d_out;

    const size_t NC  = (size_t)N_TOK * 256;
    const size_t NC2 = (size_t)N_TOK * 128;

    float* srout = (float*)d_ws;              // [343,256] fp32
    u16* base = (u16*)(srout + NR * 256);
    u16* xb      = base;                      // bf16(x)           [N,256]
    u16* yb      = xb + NC;                   // lepe linear; later kv2
    u16* lepeb   = yb + NC;                   // lepe conv out
    u16* colb    = lepeb + NC;                // im2col; later o (concat)
    u16* qb      = colb + NC;                 // q1, later q2      [N,128]
    u16* x1b     = qb + NC2;                  // [343,256]
    u16* kv1b    = x1b + NR * 256;            // [343,256]
    u16* wb_l    = kv1b + NR * 256;           // weights bf16
    u16* wb_q1   = wb_l  + 65536;
    u16* wb_q2   = wb_q1 + 32768;
    u16* wb_k1   = wb_q2 + 32768;
    u16* wb_k2   = wb_k1 + 65536;
    u16* wb_p    = wb_k2 + 65536;
    u16* wb_sr   = wb_p  + 65536;             // [256,16384]
    size_t need = (size_t)NR * 256 * 4 +
                  (4 * NC + NC2 + 2 * (size_t)NR * 256 +
                   65536 * 5 + 32768 * 2 + 4194304) * 2;
    if (ws_size < need) return;

    // 0. fp32 -> bf16 for x and all weights (q-weights pre-scaled)
    convert_all_kernel<<<dim3(9904), 256, 0, stream>>>(
        x, lepe_w, q1_w, q2_w, kv1_w, kv2_w, proj_w, sr_w,
        xb, wb_l, wb_q1, wb_q2, wb_k1, wb_k2, wb_p, wb_sr);
    // 1. y = x @ lepe_w^T + lepe_b   (bf16 out)
    gemm_bf16<<<dim3(172, 2), 256, 0, stream>>>(xb, nullptr, wb_l, lepe_b,
                                                yb, N_TOK, 256, 256, 256, 0);
    // 2. lepe = depthwise conv(y)
    dwconv_kernel<<<dim3(343, 4), 256, 0, stream>>>(yb, lconv_w, lconv_b, lepeb);
    // 3. im2col of x (bf16 out)
    im2col_kernel<<<dim3(21952), 256, 0, stream>>>(x, colb);
    // 4. srout = bias; split-K MFMA GEMM accumulates (fp32 atomics)
    init_bias_kernel<<<dim3(NR), 256, 0, stream>>>(sr_b, srout);
    gemm_bf16<<<dim3(3, 2, 8), 256, 0, stream>>>(colb, nullptr, wb_sr, nullptr,
                                                 srout, NR, 16384, 256, 2048, 2);
    // 5. x1 = gelu(layernorm(srout))  (bf16 out)
    ln_gelu_kernel<<<dim3(NR), 256, 0, stream>>>(srout, norm_g, norm_b, x1b);
    // 6. kv1 = x1 @ kv1_w^T
    gemm_bf16<<<dim3(3, 2), 256, 0, stream>>>(x1b, nullptr, wb_k1, nullptr,
                                              kv1b, NR, 256, 256, 256, 0);
    // 7. q1 = x @ q1_w^T  (scale folded in)
    gemm_bf16<<<dim3(172, 1), 256, 0, stream>>>(xb, nullptr, wb_q1, nullptr,
                                                qb, N_TOK, 256, 128, 256, 0);
    // 8. branch-1 MFMA attention -> o[:, :128]
    attn1_kernel<<<dim3(63, 4), 256, 0, stream>>>(qb, kv1b, colb);
    // 9. q2 = x @ q2_w^T
    gemm_bf16<<<dim3(172, 1), 256, 0, stream>>>(xb, nullptr, wb_q2, nullptr,
                                                qb, N_TOK, 256, 128, 256, 0);
    // 10. kv2 = x @ kv2_w^T
    gemm_bf16<<<dim3(172, 2), 256, 0, stream>>>(xb, nullptr, wb_k2, nullptr,
                                                yb, N_TOK, 256, 256, 256, 0);
    // 11. branch-2 windowed MFMA attention -> o[:, 128:]
    attn2_kernel<<<dim3(64, 4), 256, 0, stream>>>(qb, yb, colb);
    // 12. out = (o + lepe) @ proj_w^T + proj_b  (fp32 out)
    gemm_bf16<<<dim3(172, 2), 256, 0, stream>>>(colb, lepeb, wb_p, proj_b,
                                                out, N_TOK, 256, 256, 256, 1);
}

// Round 5
// 324.358 us; speedup vs baseline: 8.2971x; 1.2125x over previous
//
#include <hip/hip_runtime.h>

#define N_TOK 21952          // 28*28*28
#define NR    343            // 7*7*7
#define ATT_SCALE 0.17677669529663687f   // 32^-0.5

typedef unsigned short u16;
typedef short  v8s __attribute__((ext_vector_type(8)));
typedef float  v4f __attribute__((ext_vector_type(4)));

__device__ __forceinline__ float bf2f(unsigned u) {
    return __builtin_bit_cast(float, u << 16);
}
__device__ __forceinline__ u16 f2bf(float f) {
    unsigned u = __builtin_bit_cast(unsigned, f);
    u += 0x7fffu + ((u >> 16) & 1u);
    return (u16)(u >> 16);
}
__device__ __forceinline__ unsigned bfadd2(unsigned a, unsigned b) {
    float lo = bf2f(a & 0xffffu) + bf2f(b & 0xffffu);
    float hi = bf2f(a >> 16)     + bf2f(b >> 16);
    return (unsigned)f2bf(lo) | ((unsigned)f2bf(hi) << 16);
}

// ---------------------------------------------------------------------------
// Weight conversion fp32->bf16.
// wb_comb[768,256] = [lepe_w ; q1_w*s ; q2_w*s ; kv2_w], plus wb_k1, wb_p,
// and bias_all[768] = [lepe_b ; 0...].
// ---------------------------------------------------------------------------
#define WSEG0 16384   // lepe  (65536/4)
#define WSEG1 24576   // +q1   (32768/4)
#define WSEG2 32768   // +q2
#define WSEG3 49152   // +kv2  (65536/4)
#define WSEG4 65536   // +k1
#define WSEG5 81920   // +proj
#define WSEG6 82112   // +bias (768/4)

__global__ __launch_bounds__(256) void convert_w_kernel(
    const float* __restrict__ wl,  const float* __restrict__ wq1,
    const float* __restrict__ wq2, const float* __restrict__ wk2,
    const float* __restrict__ wk1, const float* __restrict__ wp,
    const float* __restrict__ lepe_b,
    u16* wb_comb, u16* wb_k1, u16* wb_p, float* bias_all)
{
    int gid = blockIdx.x * 256 + threadIdx.x;
    if (gid >= WSEG6) return;
    if (gid >= WSEG5) {                      // bias_all
        int b = gid - WSEG5;
        float4 v;
        int i = b * 4;
        v.x = (i + 0 < 256) ? lepe_b[i + 0] : 0.f;
        v.y = (i + 1 < 256) ? lepe_b[i + 1] : 0.f;
        v.z = (i + 2 < 256) ? lepe_b[i + 2] : 0.f;
        v.w = (i + 3 < 256) ? lepe_b[i + 3] : 0.f;
        *(float4*)(bias_all + i) = v;
        return;
    }
    const float* s; u16* d; int l; float sc = 1.f;
    if      (gid < WSEG0) { s = wl;  d = wb_comb;           l = gid; }
    else if (gid < WSEG1) { s = wq1; d = wb_comb + 65536;   l = gid - WSEG0; sc = ATT_SCALE; }
    else if (gid < WSEG2) { s = wq2; d = wb_comb + 98304;   l = gid - WSEG1; sc = ATT_SCALE; }
    else if (gid < WSEG3) { s = wk2; d = wb_comb + 131072;  l = gid - WSEG2; }
    else if (gid < WSEG4) { s = wk1; d = wb_k1;             l = gid - WSEG3; }
    else                  { s = wp;  d = wb_p;              l = gid - WSEG4; }
    float4 v = *(const float4*)(s + (size_t)l * 4);
    *(ushort4*)(d + (size_t)l * 4) =
        make_ushort4(f2bf(v.x * sc), f2bf(v.y * sc), f2bf(v.z * sc), f2bf(v.w * sc));
}

// ---------------------------------------------------------------------------
// sr_w [co][ci][tap] fp32 -> wsr_t [tap][co][ci] bf16.
// thread = (co, ci): 16 coalesced-per-lane float4 reads, 64 per-tap writes
// (wave-contiguous 128B per tap).
// ---------------------------------------------------------------------------
__global__ __launch_bounds__(256) void convert_sr_kernel(
    const float* __restrict__ wsr, u16* __restrict__ wt)
{
    int u  = blockIdx.x * 256 + threadIdx.x;   // 65536 = 256 co x 256 ci
    int co = u >> 8, ci = u & 255;
    const float* src = wsr + (size_t)co * 16384 + ci * 64;
#pragma unroll
    for (int t4 = 0; t4 < 16; t4++) {
        float4 v = *(const float4*)(src + t4 * 4);
        int t = t4 * 4;
        wt[(size_t)(t + 0) * 65536 + co * 256 + ci] = f2bf(v.x);
        wt[(size_t)(t + 1) * 65536 + co * 256 + ci] = f2bf(v.y);
        wt[(size_t)(t + 2) * 65536 + co * 256 + ci] = f2bf(v.z);
        wt[(size_t)(t + 3) * 65536 + co * 256 + ci] = f2bf(v.w);
    }
}

// ---------------------------------------------------------------------------
// bf16 MFMA GEMM: out[M,ldout] = (A [+ A2]) @ W^T [+ bias]
// 128x128 tile, BK=32, 4 waves (2x2), 4x4 mfma 16x16x32 per wave.
// a_fp32: A is fp32, converted to bf16 during staging.
// mode: 0 = bf16 out (+bias), 1 = fp32 out (+bias)
// ---------------------------------------------------------------------------
#define LDA 40   // padded LDS row stride (bf16 elems)

__global__ __launch_bounds__(256) void gemm_bf16(
    const void* __restrict__ A, const u16* __restrict__ A2,
    const u16* __restrict__ W, const float* __restrict__ bias,
    void* __restrict__ outp, int M, int K, int ldout, int a_fp32, int mode)
{
    __shared__ u16 Asm[128 * LDA];
    __shared__ u16 Bsm[128 * LDA];
    const int tid = threadIdx.x;
    const int m0 = blockIdx.x * 128;
    const int n0 = blockIdx.y * 128;
    const int wave = tid >> 6, lane = tid & 63;
    const int wm = (wave & 1) * 64, wn = (wave >> 1) * 64;
    const int fr = lane & 15, fq = lane >> 4;

    v4f acc[4][4];
#pragma unroll
    for (int i = 0; i < 4; i++)
#pragma unroll
        for (int j = 0; j < 4; j++) acc[i][j] = (v4f){0.f, 0.f, 0.f, 0.f};

    for (int kk = 0; kk < K; kk += 32) {
#pragma unroll
        for (int i = 0; i < 2; i++) {
            int u = tid + i * 256;           // 0..511
            int r = u >> 2, kc = (u & 3) * 8;
            uint4 av = make_uint4(0, 0, 0, 0);
            int m = m0 + r;
            if (m < M) {
                if (a_fp32) {
                    const float* Af = (const float*)A + (size_t)m * K + kk + kc;
                    float4 a0 = *(const float4*)Af;
                    float4 a1 = *(const float4*)(Af + 4);
                    av.x = (unsigned)f2bf(a0.x) | ((unsigned)f2bf(a0.y) << 16);
                    av.y = (unsigned)f2bf(a0.z) | ((unsigned)f2bf(a0.w) << 16);
                    av.z = (unsigned)f2bf(a1.x) | ((unsigned)f2bf(a1.y) << 16);
                    av.w = (unsigned)f2bf(a1.z) | ((unsigned)f2bf(a1.w) << 16);
                } else {
                    av = *(const uint4*)((const u16*)A + (size_t)m * K + kk + kc);
                    if (A2) {
                        uint4 bv = *(const uint4*)(A2 + (size_t)m * K + kk + kc);
                        av.x = bfadd2(av.x, bv.x); av.y = bfadd2(av.y, bv.y);
                        av.z = bfadd2(av.z, bv.z); av.w = bfadd2(av.w, bv.w);
                    }
                }
            }
            *(uint4*)(Asm + r * LDA + kc) = av;
            uint4 wv = *(const uint4*)(W + (size_t)(n0 + r) * K + kk + kc);
            *(uint4*)(Bsm + r * LDA + kc) = wv;
        }
        __syncthreads();

        v8s af[4], bfr[4];
#pragma unroll
        for (int i = 0; i < 4; i++)
            af[i] = *(const v8s*)(Asm + (wm + i * 16 + fr) * LDA + fq * 8);
#pragma unroll
        for (int j = 0; j < 4; j++)
            bfr[j] = *(const v8s*)(Bsm + (wn + j * 16 + fr) * LDA + fq * 8);
#pragma unroll
        for (int i = 0; i < 4; i++)
#pragma unroll
            for (int j = 0; j < 4; j++)
                acc[i][j] = __builtin_amdgcn_mfma_f32_16x16x32_bf16(
                    af[i], bfr[j], acc[i][j], 0, 0, 0);
        __syncthreads();
    }

    float* outf = (float*)outp;
    u16*   outb = (u16*)outp;
#pragma unroll
    for (int i = 0; i < 4; i++) {
#pragma unroll
        for (int j = 0; j < 4; j++) {
            int col = n0 + wn + j * 16 + fr;
#pragma unroll
            for (int r = 0; r < 4; r++) {
                int row = m0 + wm + i * 16 + fq * 4 + r;
                if (row >= M) continue;
                float v = acc[i][j][r];
                if (bias) v += bias[col];
                if (mode == 0) outb[(size_t)row * ldout + col] = f2bf(v);
                else           outf[(size_t)row * ldout + col] = v;
            }
        }
    }
}

// ---------------------------------------------------------------------------
// SR conv as tap-split GEMM. partials[z][p][co] = sum over taps {2z,2z+1} of
// x_rows(p,tap) @ wsr_t[tap]^T.  Grid (3, 2, 32); A staged from fp32 x with
// the stride-4 row map (no im2col).
// ---------------------------------------------------------------------------
__global__ __launch_bounds__(256) void sr_gemm(
    const float* __restrict__ x, const u16* __restrict__ Wt,
    float* __restrict__ partials)
{
    __shared__ u16 Asm[128 * LDA];
    __shared__ u16 Bsm[128 * LDA];
    const int tid = threadIdx.x;
    const int m0 = blockIdx.x * 128;   // p tile
    const int n0 = blockIdx.y * 128;   // co tile
    const int z  = blockIdx.z;         // taps 2z, 2z+1
    const int wave = tid >> 6, lane = tid & 63;
    const int wm = (wave & 1) * 64, wn = (wave >> 1) * 64;
    const int fr = lane & 15, fq = lane >> 4;

    v4f acc[4][4];
#pragma unroll
    for (int i = 0; i < 4; i++)
#pragma unroll
        for (int j = 0; j < 4; j++) acc[i][j] = (v4f){0.f, 0.f, 0.f, 0.f};

    for (int it = 0; it < 16; it++) {
        int tap = z * 2 + (it >> 3);
        int ci0 = (it & 7) * 32;
        int kz = tap >> 4, ky = (tap >> 2) & 3, kx = tap & 3;
#pragma unroll
        for (int i = 0; i < 2; i++) {
            int u = tid + i * 256;
            int r = u >> 2, seg = (u & 3) * 8;
            uint4 av = make_uint4(0, 0, 0, 0);
            int p = m0 + r;
            if (p < NR) {
                int pz = p / 49, pr = p % 49, py = pr / 7, px = pr % 7;
                int n = (pz * 4 + kz) * 784 + (py * 4 + ky) * 28 + (px * 4 + kx);
                const float* src = x + (size_t)n * 256 + ci0 + seg;
                float4 a0 = *(const float4*)src;
                float4 a1 = *(const float4*)(src + 4);
                av.x = (unsigned)f2bf(a0.x) | ((unsigned)f2bf(a0.y) << 16);
                av.y = (unsigned)f2bf(a0.z) | ((unsigned)f2bf(a0.w) << 16);
                av.z = (unsigned)f2bf(a1.x) | ((unsigned)f2bf(a1.y) << 16);
                av.w = (unsigned)f2bf(a1.z) | ((unsigned)f2bf(a1.w) << 16);
            }
            *(uint4*)(Asm + r * LDA + seg) = av;
            uint4 wv = *(const uint4*)(Wt + (size_t)tap * 65536 +
                                       (size_t)(n0 + r) * 256 + ci0 + seg);
            *(uint4*)(Bsm + r * LDA + seg) = wv;
        }
        __syncthreads();

        v8s af[4], bfr[4];
#pragma unroll
        for (int i = 0; i < 4; i++)
            af[i] = *(const v8s*)(Asm + (wm + i * 16 + fr) * LDA + fq * 8);
#pragma unroll
        for (int j = 0; j < 4; j++)
            bfr[j] = *(const v8s*)(Bsm + (wn + j * 16 + fr) * LDA + fq * 8);
#pragma unroll
        for (int i = 0; i < 4; i++)
#pragma unroll
            for (int j = 0; j < 4; j++)
                acc[i][j] = __builtin_amdgcn_mfma_f32_16x16x32_bf16(
                    af[i], bfr[j], acc[i][j], 0, 0, 0);
        __syncthreads();
    }

    float* dst = partials + (size_t)z * (NR * 256);
#pragma unroll
    for (int i = 0; i < 4; i++) {
#pragma unroll
        for (int j = 0; j < 4; j++) {
            int col = n0 + wn + j * 16 + fr;
#pragma unroll
            for (int r = 0; r < 4; r++) {
                int row = m0 + wm + i * 16 + fq * 4 + r;
                if (row < NR) dst[(size_t)row * 256 + col] = acc[i][j][r];
            }
        }
    }
}

// ---------------------------------------------------------------------------
// Reduce 32 partials + sr bias, LayerNorm (C=256) + exact GELU -> bf16.
// ---------------------------------------------------------------------------
__global__ __launch_bounds__(256) void ln_gelu_kernel(
    const float* __restrict__ partials, const float* __restrict__ srb,
    const float* __restrict__ g, const float* __restrict__ b,
    u16* __restrict__ out)
{
    int row = blockIdx.x, c = threadIdx.x;
    float v = srb[c];
#pragma unroll
    for (int s = 0; s < 32; s++)
        v += partials[(size_t)s * (NR * 256) + row * 256 + c];
    float s1 = v, s2 = v * v;
#pragma unroll
    for (int off = 1; off < 64; off <<= 1) {
        s1 += __shfl_xor(s1, off);
        s2 += __shfl_xor(s2, off);
    }
    __shared__ float ws[4], ws2[4];
    int wave = c >> 6, lane = c & 63;
    if (lane == 0) { ws[wave] = s1; ws2[wave] = s2; }
    __syncthreads();
    float mean = (ws[0] + ws[1] + ws[2] + ws[3]) * (1.f / 256.f);
    float m2   = (ws2[0] + ws2[1] + ws2[2] + ws2[3]) * (1.f / 256.f);
    float var  = m2 - mean * mean;
    float xn = (v - mean) * rsqrtf(var + 1e-5f) * g[c] + b[c];
    out[row * 256 + c] = f2bf(0.5f * xn * (1.f + erff(xn * 0.70710678118654752f)));
}

// ---------------------------------------------------------------------------
// Depthwise 3x3x3 SAME conv, LDS-tiled.  y = xall cols 0..255 (row stride 768).
// ---------------------------------------------------------------------------
__global__ __launch_bounds__(256) void dwconv_kernel(
    const u16* __restrict__ xall, const float* __restrict__ w,
    const float* __restrict__ bias, u16* __restrict__ out)
{
    __shared__ float sm[216 * 64];
    __shared__ float sw[64 * 27];
    const int tid = threadIdx.x;
    const int t  = blockIdx.x;
    const int g  = blockIdx.y;
    const int tz = t / 49, tr = t % 49, ty = tr / 7, tx = tr % 7;

    for (int u = tid; u < 64 * 27; u += 256) sw[u] = w[g * 64 * 27 + u];

    for (int u = tid; u < 216 * 8; u += 256) {
        int r = u >> 3, c8 = (u & 7) * 8;
        int vz = tz * 4 - 1 + r / 36;
        int rem = r % 36;
        int vy = ty * 4 - 1 + rem / 6;
        int vx = tx * 4 - 1 + rem % 6;
        float f[8];
        if ((unsigned)vz < 28u && (unsigned)vy < 28u && (unsigned)vx < 28u) {
            int n = vz * 784 + vy * 28 + vx;
            uint4 raw = *(const uint4*)(xall + (size_t)n * 768 + g * 64 + c8);
            f[0] = bf2f(raw.x & 0xffffu); f[1] = bf2f(raw.x >> 16);
            f[2] = bf2f(raw.y & 0xffffu); f[3] = bf2f(raw.y >> 16);
            f[4] = bf2f(raw.z & 0xffffu); f[5] = bf2f(raw.z >> 16);
            f[6] = bf2f(raw.w & 0xffffu); f[7] = bf2f(raw.w >> 16);
        } else {
#pragma unroll
            for (int i = 0; i < 8; i++) f[i] = 0.f;
        }
        float* dst = &sm[r * 64 + c8];
        *(float4*)dst       = make_float4(f[0], f[1], f[2], f[3]);
        *(float4*)(dst + 4) = make_float4(f[4], f[5], f[6], f[7]);
    }
    __syncthreads();

    const int c  = tid & 63;
    const int ch = g * 64 + c;
    float wreg[27];
#pragma unroll
    for (int j = 0; j < 27; j++) wreg[j] = sw[c * 27 + j];
    const float bc = bias[ch];

    const int vbase = (tid >> 6) * 16;
    for (int v = vbase; v < vbase + 16; v++) {
        int vz = v >> 4, vy = (v >> 2) & 3, vx = v & 3;
        float a = bc;
#pragma unroll
        for (int dz = 0; dz < 3; dz++)
#pragma unroll
            for (int dy = 0; dy < 3; dy++)
#pragma unroll
                for (int dx = 0; dx < 3; dx++)
                    a = fmaf(sm[((vz + dz) * 36 + (vy + dy) * 6 + (vx + dx)) * 64 + c],
                             wreg[dz * 9 + dy * 3 + dx], a);
        int n = (tz * 4 + vz) * 784 + (ty * 4 + vy) * 28 + (tx * 4 + vx);
        out[(size_t)n * 256 + ch] = f2bf(a);
    }
}

// ===========================================================================
// MFMA attention (same structure as round 4, strides updated for xall).
//   A-frag: lane holds A[m = lane&15][k = (lane>>4)*8 + j]
//   B-frag: lane holds W[n = lane&15][k = (lane>>4)*8 + j]
//   C/D   : lane&15 = col, (lane>>4)*4 + reg = row
// ===========================================================================
#define KP  40    // K LDS row stride (bf16)
#define VTP 360   // V^T LDS row stride (bf16)
#define PP  40    // P LDS row stride (bf16)

// Branch 1: q = xall cols 256..383 (stride 768); kv1: [343,256].
__global__ __launch_bounds__(256) void attn1_kernel(
    const u16* __restrict__ xall, const u16* __restrict__ kv1,
    u16* __restrict__ o)
{
    __shared__ u16 Ks[352 * KP];
    __shared__ u16 VTs[32 * VTP];
    __shared__ u16 Ps[4 * 16 * PP];
    const int tid = threadIdx.x;
    const int h = blockIdx.y;
    const int qbase = blockIdx.x * 352;
    const int wave = tid >> 6, lane = tid & 63;
    const int fr = lane & 15, fq = lane >> 4;

    for (int u = tid; u < 352 * 4; u += 256) {
        int r = u >> 2, seg = u & 3;
        uint4 kq = make_uint4(0, 0, 0, 0), vq = make_uint4(0, 0, 0, 0);
        if (r < NR) {
            kq = *(const uint4*)(kv1 + (size_t)r * 256 + h * 32 + seg * 8);
            vq = *(const uint4*)(kv1 + (size_t)r * 256 + 128 + h * 32 + seg * 8);
        }
        *(uint4*)(Ks + r * KP + seg * 8) = kq;
        int d0 = seg * 8;
        VTs[(d0 + 0) * VTP + r] = (u16)(vq.x & 0xffffu);
        VTs[(d0 + 1) * VTP + r] = (u16)(vq.x >> 16);
        VTs[(d0 + 2) * VTP + r] = (u16)(vq.y & 0xffffu);
        VTs[(d0 + 3) * VTP + r] = (u16)(vq.y >> 16);
        VTs[(d0 + 4) * VTP + r] = (u16)(vq.z & 0xffffu);
        VTs[(d0 + 5) * VTP + r] = (u16)(vq.z >> 16);
        VTs[(d0 + 6) * VTP + r] = (u16)(vq.w & 0xffffu);
        VTs[(d0 + 7) * VTP + r] = (u16)(vq.w >> 16);
    }
    __syncthreads();

    u16* Pw = Ps + wave * 16 * PP;
    for (int mt = wave; mt < 22; mt += 4) {
        int qrow = qbase + mt * 16 + fr;
        v8s aq = {0, 0, 0, 0, 0, 0, 0, 0};
        if (qrow < N_TOK)
            aq = *(const v8s*)(xall + (size_t)qrow * 768 + 256 + h * 32 + fq * 8);

        v4f s[22];
#pragma unroll
        for (int t = 0; t < 22; t++) {
            v8s bk = *(const v8s*)(Ks + (t * 16 + fr) * KP + fq * 8);
            s[t] = __builtin_amdgcn_mfma_f32_16x16x32_bf16(
                aq, bk, (v4f){0.f, 0.f, 0.f, 0.f}, 0, 0, 0);
        }
        if (fr >= 7) {
#pragma unroll
            for (int r = 0; r < 4; r++) s[21][r] = -1e30f;
        }

        float inv_l[4];
#pragma unroll
        for (int r = 0; r < 4; r++) {
            float m = s[0][r];
#pragma unroll
            for (int t = 1; t < 22; t++) m = fmaxf(m, s[t][r]);
#pragma unroll
            for (int off = 1; off < 16; off <<= 1) m = fmaxf(m, __shfl_xor(m, off));
            float l = 0.f;
#pragma unroll
            for (int t = 0; t < 22; t++) {
                v4f sv = s[t];
                float p = __expf(sv[r] - m);
                sv[r] = p; s[t] = sv;
                l += p;
            }
#pragma unroll
            for (int off = 1; off < 16; off <<= 1) l += __shfl_xor(l, off);
            inv_l[r] = 1.f / l;
        }

        v4f o0 = {0.f, 0.f, 0.f, 0.f}, o1 = {0.f, 0.f, 0.f, 0.f};
#pragma unroll
        for (int kt = 0; kt < 11; kt++) {
#pragma unroll
            for (int tt = 0; tt < 2; tt++) {
                int t = kt * 2 + tt;
#pragma unroll
                for (int r = 0; r < 4; r++)
                    Pw[(fq * 4 + r) * PP + tt * 16 + fr] = f2bf(s[t][r]);
            }
            __asm__ volatile("s_waitcnt lgkmcnt(0)" ::: "memory");
            v8s ap  = *(const v8s*)(Pw + fr * PP + fq * 8);
            v8s bv0 = *(const v8s*)(VTs + fr * VTP + kt * 32 + fq * 8);
            v8s bv1 = *(const v8s*)(VTs + (16 + fr) * VTP + kt * 32 + fq * 8);
            o0 = __builtin_amdgcn_mfma_f32_16x16x32_bf16(ap, bv0, o0, 0, 0, 0);
            o1 = __builtin_amdgcn_mfma_f32_16x16x32_bf16(ap, bv1, o1, 0, 0, 0);
        }

#pragma unroll
        for (int r = 0; r < 4; r++) {
            int n = qbase + mt * 16 + fq * 4 + r;
            if (n < N_TOK) {
                u16* op = o + (size_t)n * 256 + h * 32;
                op[fr]      = f2bf(o0[r] * inv_l[r]);
                op[16 + fr] = f2bf(o1[r] * inv_l[r]);
            }
        }
    }
}

// Branch 2: q = xall cols 384..511; kv2 = xall cols 512..767 (stride 768).
__global__ __launch_bounds__(256) void attn2_kernel(
    const u16* __restrict__ xall, u16* __restrict__ o)
{
    __shared__ u16 Ks[352 * KP];
    __shared__ u16 VTs[32 * VTP];
    __shared__ u16 Ps[4 * 16 * PP];
    const int tid = threadIdx.x;
    const int h  = blockIdx.y;
    const int wi = blockIdx.x;
    const int zb = (wi >> 4) & 3, yb = (wi >> 2) & 3, xb = wi & 3;
    const int wave = tid >> 6, lane = tid & 63;
    const int fr = lane & 15, fq = lane >> 4;

    for (int u = tid; u < 352 * 4; u += 256) {
        int r = u >> 2, seg = u & 3;
        uint4 kq = make_uint4(0, 0, 0, 0), vq = make_uint4(0, 0, 0, 0);
        if (r < NR) {
            int mz = r / 49, mr = r % 49, my = mr / 7, mx = mr % 7;
            int nk = (zb * 7 + mz) * 784 + (yb * 7 + my) * 28 + (xb * 7 + mx);
            const u16* base = xall + (size_t)nk * 768 + 512;
            kq = *(const uint4*)(base + h * 32 + seg * 8);
            vq = *(const uint4*)(base + 128 + h * 32 + seg * 8);
        }
        *(uint4*)(Ks + r * KP + seg * 8) = kq;
        int d0 = seg * 8;
        VTs[(d0 + 0) * VTP + r] = (u16)(vq.x & 0xffffu);
        VTs[(d0 + 1) * VTP + r] = (u16)(vq.x >> 16);
        VTs[(d0 + 2) * VTP + r] = (u16)(vq.y & 0xffffu);
        VTs[(d0 + 3) * VTP + r] = (u16)(vq.y >> 16);
        VTs[(d0 + 4) * VTP + r] = (u16)(vq.z & 0xffffu);
        VTs[(d0 + 5) * VTP + r] = (u16)(vq.z >> 16);
        VTs[(d0 + 6) * VTP + r] = (u16)(vq.w & 0xffffu);
        VTs[(d0 + 7) * VTP + r] = (u16)(vq.w >> 16);
    }
    __syncthreads();

    u16* Pw = Ps + wave * 16 * PP;
    for (int mt = wave; mt < 22; mt += 4) {
        int tw = mt * 16 + fr;
        v8s aq = {0, 0, 0, 0, 0, 0, 0, 0};
        if (tw < NR) {
            int wz = tw / 49, tr2 = tw % 49, wy = tr2 / 7, wx = tr2 % 7;
            int nq = (zb * 7 + wz) * 784 + (yb * 7 + wy) * 28 + (xb * 7 + wx);
            aq = *(const v8s*)(xall + (size_t)nq * 768 + 384 + h * 32 + fq * 8);
        }

        v4f s[22];
#pragma unroll
        for (int t = 0; t < 22; t++) {
            v8s bk = *(const v8s*)(Ks + (t * 16 + fr) * KP + fq * 8);
            s[t] = __builtin_amdgcn_mfma_f32_16x16x32_bf16(
                aq, bk, (v4f){0.f, 0.f, 0.f, 0.f}, 0, 0, 0);
        }
        if (fr >= 7) {
#pragma unroll
            for (int r = 0; r < 4; r++) s[21][r] = -1e30f;
        }

        float inv_l[4];
#pragma unroll
        for (int r = 0; r < 4; r++) {
            float m = s[0][r];
#pragma unroll
            for (int t = 1; t < 22; t++) m = fmaxf(m, s[t][r]);
#pragma unroll
            for (int off = 1; off < 16; off <<= 1) m = fmaxf(m, __shfl_xor(m, off));
            float l = 0.f;
#pragma unroll
            for (int t = 0; t < 22; t++) {
                v4f sv = s[t];
                float p = __expf(sv[r] - m);
                sv[r] = p; s[t] = sv;
                l += p;
            }
#pragma unroll
            for (int off = 1; off < 16; off <<= 1) l += __shfl_xor(l, off);
            inv_l[r] = 1.f / l;
        }

        v4f o0 = {0.f, 0.f, 0.f, 0.f}, o1 = {0.f, 0.f, 0.f, 0.f};
#pragma unroll
        for (int kt = 0; kt < 11; kt++) {
#pragma unroll
            for (int tt = 0; tt < 2; tt++) {
                int t = kt * 2 + tt;
#pragma unroll
                for (int r = 0; r < 4; r++)
                    Pw[(fq * 4 + r) * PP + tt * 16 + fr] = f2bf(s[t][r]);
            }
            __asm__ volatile("s_waitcnt lgkmcnt(0)" ::: "memory");
            v8s ap  = *(const v8s*)(Pw + fr * PP + fq * 8);
            v8s bv0 = *(const v8s*)(VTs + fr * VTP + kt * 32 + fq * 8);
            v8s bv1 = *(const v8s*)(VTs + (16 + fr) * VTP + kt * 32 + fq * 8);
            o0 = __builtin_amdgcn_mfma_f32_16x16x32_bf16(ap, bv0, o0, 0, 0, 0);
            o1 = __builtin_amdgcn_mfma_f32_16x16x32_bf16(ap, bv1, o1, 0, 0, 0);
        }

#pragma unroll
        for (int r = 0; r < 4; r++) {
            int ts = mt * 16 + fq * 4 + r;
            if (ts < NR) {
                int wz = ts / 49, tr2 = ts % 49, wy = tr2 / 7, wx = tr2 % 7;
                int nq = (zb * 7 + wz) * 784 + (yb * 7 + wy) * 28 + (xb * 7 + wx);
                u16* op = o + (size_t)nq * 256 + 128 + h * 32;
                op[fr]      = f2bf(o0[r] * inv_l[r]);
                op[16 + fr] = f2bf(o1[r] * inv_l[r]);
            }
        }
    }
}

// ---------------------------------------------------------------------------
extern "C" void kernel_launch(void* const* d_in, const int* in_sizes, int n_in,
                              void* d_out, int out_size, void* d_ws, size_t ws_size,
                              hipStream_t stream)
{
    const float* x       = (const float*)d_in[0];
    const float* lepe_w  = (const float*)d_in[4];
    const float* lepe_b  = (const float*)d_in[5];
    const float* lconv_w = (const float*)d_in[6];
    const float* lconv_b = (const float*)d_in[7];
    const float* sr_w    = (const float*)d_in[8];
    const float* sr_b    = (const float*)d_in[9];
    const float* norm_g  = (const float*)d_in[10];
    const float* norm_b  = (const float*)d_in[11];
    const float* q1_w    = (const float*)d_in[12];
    const float* kv1_w   = (const float*)d_in[13];
    const float* q2_w    = (const float*)d_in[14];
    const float* kv2_w   = (const float*)d_in[15];
    const float* proj_w  = (const float*)d_in[16];
    const float* proj_b  = (const float*)d_in[17];
    float* out = (float*)d_out;

    const size_t NC = (size_t)N_TOK * 256;

    float* partials = (float*)d_ws;                 // [32][343*256] fp32
    float* bias_all = partials + 32 * (NR * 256);   // [768]
    u16* xall   = (u16*)(bias_all + 768);           // [N,768]: y|q1|q2|kv2
    u16* lepeb  = xall + (size_t)N_TOK * 768;       // [N,256]
    u16* colb   = lepeb + NC;                       // o concat [N,256]
    u16* x1b    = colb + NC;                        // [343,256]
    u16* kv1b   = x1b + NR * 256;                   // [343,256]
    u16* wb_comb = kv1b + NR * 256;                 // [768,256]
    u16* wb_k1  = wb_comb + 196608;                 // [256,256]
    u16* wb_p   = wb_k1 + 65536;                    // [256,256]
    u16* wsr_t  = wb_p + 65536;                     // [64][256,256]
    size_t need = (size_t)(32 * NR * 256 + 768) * 4 +
                  ((size_t)N_TOK * 768 + 2 * NC + 2 * (size_t)NR * 256 +
                   196608 + 2 * 65536 + 4194304) * 2;
    if (ws_size < need) return;

    // 0a. weights -> bf16 (q pre-scaled), bias_all
    convert_w_kernel<<<dim3(321), 256, 0, stream>>>(
        lepe_w, q1_w, q2_w, kv2_w, kv1_w, proj_w, lepe_b,
        wb_comb, wb_k1, wb_p, bias_all);
    // 0b. sr_w -> [tap][co][ci] bf16
    convert_sr_kernel<<<dim3(256), 256, 0, stream>>>(sr_w, wsr_t);
    // 1. xall = x @ [lepe|q1|q2|kv2]^T + bias_all   (fp32 A, bf16 out)
    gemm_bf16<<<dim3(172, 6), 256, 0, stream>>>(x, nullptr, wb_comb, bias_all,
                                                xall, N_TOK, 256, 768, 1, 0);
    // 2. lepe = depthwise conv(y)
    dwconv_kernel<<<dim3(343, 4), 256, 0, stream>>>(xall, lconv_w, lconv_b, lepeb);
    // 3. SR conv: tap-split GEMM into partials
    sr_gemm<<<dim3(3, 2, 32), 256, 0, stream>>>(x, wsr_t, partials);
    // 4. x1 = gelu(layernorm(sum partials + sr_b))
    ln_gelu_kernel<<<dim3(NR), 256, 0, stream>>>(partials, sr_b, norm_g, norm_b, x1b);
    // 5. kv1 = x1 @ kv1_w^T
    gemm_bf16<<<dim3(3, 2), 256, 0, stream>>>(x1b, nullptr, wb_k1, nullptr,
                                              kv1b, NR, 256, 256, 0, 0);
    // 6. branch-1 MFMA attention -> o[:, :128]
    attn1_kernel<<<dim3(63, 4), 256, 0, stream>>>(xall, kv1b, colb);
    // 7. branch-2 windowed MFMA attention -> o[:, 128:]
    attn2_kernel<<<dim3(64, 4), 256, 0, stream>>>(xall, colb);
    // 8. out = (o + lepe) @ proj_w^T + proj_b  (fp32 out)
    gemm_bf16<<<dim3(172, 2), 256, 0, stream>>>(colb, lepeb, wb_p, proj_b,
                                                out, N_TOK, 256, 256, 0, 1);
}